// Round 1
// baseline (4460.087 us; speedup 1.0000x reference)
//
#include <hip/hip_runtime.h>

// GNN_44942537785535 — MI355X bf16-MFMA implementation.
// N=4096, D=512, H=8, DH=64, E=131072, L=2.
// Attention uses the reference's raw-reshape semantics: Q/K/V [N,D] buffers are
// reinterpreted flat as [512][4096] (row p=h*64+d, col m), output written flat
// as [H][N][DH] and consumed as [N,D]. All pure index arithmetic, no data moves.
// Workspace requirement: ~44.1 MB (guarded).

#define NN 4096
#define DD 512
#define HH 8
#define DH 64
#define EE 131072

typedef float f32x4 __attribute__((ext_vector_type(4)));
typedef short short8 __attribute__((ext_vector_type(8)));
typedef __bf16 bf16x8 __attribute__((ext_vector_type(8)));

static __device__ __forceinline__ unsigned short f2bf(float f) {
  unsigned u = __float_as_uint(f);
  return (unsigned short)((u + 0x7FFFu + ((u >> 16) & 1u)) >> 16);  // RNE
}

static __device__ __forceinline__ short8 pack8(f32x4 a, f32x4 b) {
  short8 s;
#pragma unroll
  for (int j = 0; j < 4; ++j) {
    s[j] = (short)f2bf(a[j]);
    s[j + 4] = (short)f2bf(b[j]);
  }
  return s;
}

static __device__ __forceinline__ f32x4 mfma16(short8 a, short8 b, f32x4 c) {
  return __builtin_amdgcn_mfma_f32_16x16x32_bf16(
      __builtin_bit_cast(bf16x8, a), __builtin_bit_cast(bf16x8, b), c, 0, 0, 0);
}

// ---------------------------------------------------------------- degree/dinv
__global__ __launch_bounds__(256) void deg_k(const int* __restrict__ ei, float* __restrict__ deg) {
  int t = blockIdx.x * 256 + threadIdx.x;
  atomicAdd(&deg[ei[EE + t]], 1.0f);  // dst-degree
}

__global__ __launch_bounds__(256) void dinv_k(const float* __restrict__ deg, float* __restrict__ dinv) {
  int t = blockIdx.x * 256 + threadIdx.x;
  float dg = deg[t];
  dinv[t] = dg > 0.f ? rsqrtf(fmaxf(dg, 1e-12f)) : 0.f;
}

// ---------------------------------------------------------------- GEMM (bf16 MFMA)
// C[M,Nc] = A[M,K] @ (TRANS_B ? B^T : B), epilogue (acc + bias) * scale.
// Tile 128x64, 4 waves, each wave 32x64 (2x4 frags of 16x16), BK=32.
template <bool TRANS_B, bool HAS_BIAS, bool OUT_BF16>
__global__ __launch_bounds__(256) void gemm_k(const float* __restrict__ A,
                                              const float* __restrict__ B,
                                              const float* __restrict__ bias, float scale,
                                              void* __restrict__ Cv, int M, int Nc, int K) {
  __shared__ __align__(16) unsigned short a_sm[128][40];
  __shared__ __align__(16) unsigned short b_sm[64][40];
  const int tid = threadIdx.x;
  const int w = tid >> 6, lane = tid & 63, g = lane >> 4, c16 = lane & 15;
  const int m0 = blockIdx.y * 128, n0 = blockIdx.x * 64;
  const int wm = w * 32;
  f32x4 acc[2][4] = {};

  const int ar = tid >> 1, ac = (tid & 1) * 16;
  for (int k0 = 0; k0 < K; k0 += 32) {
    // issue global loads (registers) before the barrier
    const float* asrc = A + (size_t)(m0 + ar) * K + k0 + ac;
    f32x4 av0 = *(const f32x4*)(asrc + 0);
    f32x4 av1 = *(const f32x4*)(asrc + 4);
    f32x4 av2 = *(const f32x4*)(asrc + 8);
    f32x4 av3 = *(const f32x4*)(asrc + 12);
    f32x4 bv0, bv1;
    int br = 0, bc = 0, bk_ = 0, bn = 0;
    if (TRANS_B) {
      br = tid >> 2; bc = (tid & 3) * 8;
      const float* bsrc = B + (size_t)(n0 + br) * K + k0 + bc;
      bv0 = *(const f32x4*)(bsrc);
      bv1 = *(const f32x4*)(bsrc + 4);
    } else {
      bk_ = tid >> 3; bn = (tid & 7) * 8;
      const float* bsrc = B + (size_t)(k0 + bk_) * Nc + n0 + bn;
      bv0 = *(const f32x4*)(bsrc);
      bv1 = *(const f32x4*)(bsrc + 4);
    }
    __syncthreads();  // prior tile fully consumed
    *(short8*)&a_sm[ar][ac] = pack8(av0, av1);
    *(short8*)&a_sm[ar][ac + 8] = pack8(av2, av3);
    if (TRANS_B) {
      *(short8*)&b_sm[br][bc] = pack8(bv0, bv1);
    } else {
#pragma unroll
      for (int j = 0; j < 4; ++j) {
        b_sm[bn + j][bk_] = f2bf(bv0[j]);
        b_sm[bn + 4 + j][bk_] = f2bf(bv1[j]);
      }
    }
    __syncthreads();
    short8 af0 = *(const short8*)&a_sm[wm + c16][g * 8];
    short8 af1 = *(const short8*)&a_sm[wm + 16 + c16][g * 8];
#pragma unroll
    for (int fn = 0; fn < 4; ++fn) {
      short8 bf = *(const short8*)&b_sm[fn * 16 + c16][g * 8];
      acc[0][fn] = mfma16(af0, bf, acc[0][fn]);
      acc[1][fn] = mfma16(af1, bf, acc[1][fn]);
    }
  }
#pragma unroll
  for (int fm = 0; fm < 2; ++fm)
#pragma unroll
    for (int fn = 0; fn < 4; ++fn)
#pragma unroll
      for (int r = 0; r < 4; ++r) {
        int row = m0 + wm + fm * 16 + g * 4 + r;
        int col = n0 + fn * 16 + c16;
        float v = acc[fm][fn][r];
        if (HAS_BIAS) v += bias[col];
        v *= scale;
        if (OUT_BF16)
          ((unsigned short*)Cv)[(size_t)row * Nc + col] = f2bf(v);
        else
          ((float*)Cv)[(size_t)row * Nc + col] = v;
      }
}

// ---------------------------------------------------------------- edge scatter
__global__ __launch_bounds__(256) void scatter_k(const float* __restrict__ h0,
                                                 const int* __restrict__ ei,
                                                 const float* __restrict__ dinv,
                                                 float* __restrict__ h1) {
  const int w = threadIdx.x >> 6, lane = threadIdx.x & 63;
  const int e = blockIdx.x * 4 + w;
  const int s = ei[e], d = ei[EE + e];
  const float en = dinv[s] * dinv[d];
  const float* src = h0 + (size_t)s * DD + lane * 8;
  float* dst = h1 + (size_t)d * DD + lane * 8;
  f32x4 v0 = *(const f32x4*)(src);
  f32x4 v1 = *(const f32x4*)(src + 4);
#pragma unroll
  for (int j = 0; j < 4; ++j) {
    atomicAdd(dst + j, v0[j] * en);
    atomicAdd(dst + 4 + j, v1[j] * en);
  }
}

// ---------------------------------------------------------------- PairNorm stats
__global__ __launch_bounds__(256) void colstat_k(const float* __restrict__ hin,
                                                 float* __restrict__ colsum,
                                                 float* __restrict__ sumsq) {
  const int t = threadIdx.x;
  const int r0 = blockIdx.x * 128;
  float a0 = 0.f, a1 = 0.f, sq = 0.f;
  for (int r = 0; r < 128; ++r) {
    float v0 = hin[(size_t)(r0 + r) * DD + t];
    float v1 = hin[(size_t)(r0 + r) * DD + 256 + t];
    a0 += v0; a1 += v1;
    sq += v0 * v0 + v1 * v1;
  }
  atomicAdd(&colsum[t], a0);
  atomicAdd(&colsum[t + 256], a1);
#pragma unroll
  for (int m = 1; m <= 32; m <<= 1) sq += __shfl_xor(sq, m);
  __shared__ float rr[4];
  int w = t >> 6, lane = t & 63;
  if (lane == 0) rr[w] = sq;
  __syncthreads();
  if (t == 0) atomicAdd(sumsq, rr[0] + rr[1] + rr[2] + rr[3]);
}

__global__ __launch_bounds__(256) void finalize_pn_k(const float* __restrict__ colsum,
                                                     const float* __restrict__ sumsq,
                                                     float* __restrict__ mu,
                                                     float* __restrict__ rnp) {
  const int t = threadIdx.x;
  float m0 = colsum[t] * (1.f / (float)NN);
  float m1 = colsum[t + 256] * (1.f / (float)NN);
  mu[t] = m0;
  mu[t + 256] = m1;
  float sq = m0 * m0 + m1 * m1;
#pragma unroll
  for (int m = 1; m <= 32; m <<= 1) sq += __shfl_xor(sq, m);
  __shared__ float rr[4];
  int w = t >> 6, lane = t & 63;
  if (lane == 0) rr[w] = sq;
  __syncthreads();
  if (t == 0) {
    float musq = rr[0] + rr[1] + rr[2] + rr[3];
    *rnp = rsqrtf(1e-5f + (*sumsq) * (1.f / (float)NN) - musq);
  }
}

// ---------------------------------------------------------------- fused row ops
// PN=true:  h=(hin-mu)*rn; h=relu(h)+h; LayerNorm(g,b)
// PN=false: LayerNorm(hin, g, b)
template <bool PN>
__global__ __launch_bounds__(256) void rowfuse_k(const float* __restrict__ hin,
                                                 const float* __restrict__ mu,
                                                 const float* __restrict__ rnp,
                                                 const float* __restrict__ gg,
                                                 const float* __restrict__ bb,
                                                 float* __restrict__ outp) {
  const int row = blockIdx.x, t = threadIdx.x;
  const size_t base = (size_t)row * DD;
  float v0 = hin[base + t], v1 = hin[base + 256 + t];
  if (PN) {
    float rn = *rnp;
    v0 = (v0 - mu[t]) * rn;
    v1 = (v1 - mu[t + 256]) * rn;
    v0 = fmaxf(v0, 0.f) + v0;
    v1 = fmaxf(v1, 0.f) + v1;
  }
  float s1 = v0 + v1, s2 = v0 * v0 + v1 * v1;
#pragma unroll
  for (int m = 1; m <= 32; m <<= 1) {
    s1 += __shfl_xor(s1, m);
    s2 += __shfl_xor(s2, m);
  }
  __shared__ float r1[4], r2[4];
  int w = t >> 6, lane = t & 63;
  if (lane == 0) { r1[w] = s1; r2[w] = s2; }
  __syncthreads();
  s1 = r1[0] + r1[1] + r1[2] + r1[3];
  s2 = r2[0] + r2[1] + r2[2] + r2[3];
  float mean = s1 * (1.f / (float)DD);
  float var = s2 * (1.f / (float)DD) - mean * mean;
  float inv = rsqrtf(var + 1e-5f);
  outp[base + t] = (v0 - mean) * inv * gg[t] + bb[t];
  outp[base + 256 + t] = (v1 - mean) * inv * gg[t + 256] + bb[t + 256];
}

// ---------------------------------------------------------------- [512][4096] -> [4096][512] bf16 transpose
__global__ __launch_bounds__(256) void transpose_pk(const unsigned short* __restrict__ in,
                                                    unsigned short* __restrict__ out) {
  __shared__ __align__(16) unsigned short sm[64][72];
  const int m0 = blockIdx.x * 64, p0 = blockIdx.y * 64;
  const int t = threadIdx.x;
  const int r = t >> 2, q = (t & 3) * 16;
  *(short8*)&sm[r][q] = *(const short8*)&in[(size_t)(p0 + r) * NN + m0 + q];
  *(short8*)&sm[r][q + 8] = *(const short8*)&in[(size_t)(p0 + r) * NN + m0 + q + 8];
  __syncthreads();
  short8 s0, s1;
#pragma unroll
  for (int j = 0; j < 8; ++j) {
    s0[j] = (short)sm[q + j][r];
    s1[j] = (short)sm[q + 8 + j][r];
  }
  *(short8*)&out[(size_t)(m0 + r) * DD + p0 + q] = s0;
  *(short8*)&out[(size_t)(m0 + r) * DD + p0 + q + 8] = s1;
}

// ---------------------------------------------------------------- flash attention (scrambled-view heads)
// Qt/Kt: [4096][512] bf16 (row m/l, col p=h*64+d). Vb: flat [512][4096] view.
// Out: f32 written at flat [h][l][d] (= [N,D] reinterpretation).
// Grid (64, 8); block 256 = 4 independent waves; wave handles 16 l-rows.
__global__ __launch_bounds__(256) void attn_k(const unsigned short* __restrict__ Qt,
                                              const unsigned short* __restrict__ Kt,
                                              const unsigned short* __restrict__ Vb,
                                              float* __restrict__ Out) {
  __shared__ __align__(16) unsigned short p_sm[4][16][136];
  const int tid = threadIdx.x, w = tid >> 6, lane = tid & 63;
  const int g = lane >> 4, c16 = lane & 15;
  const int h = blockIdx.y;
  const int l0 = blockIdx.x * 64 + w * 16;

  short8 qf[2];
  qf[0] = *(const short8*)&Qt[(size_t)(l0 + c16) * DD + h * 64 + g * 8];
  qf[1] = *(const short8*)&Qt[(size_t)(l0 + c16) * DD + h * 64 + 32 + g * 8];

  float mrun[4], srun[4];
  f32x4 oacc[4] = {};
#pragma unroll
  for (int r = 0; r < 4; ++r) { mrun[r] = -1e30f; srun[r] = 0.f; }

  for (int m0 = 0; m0 < NN; m0 += 128) {
    f32x4 sf[8] = {};
#pragma unroll
    for (int fn = 0; fn < 8; ++fn) {
      const size_t kb = (size_t)(m0 + fn * 16 + c16) * DD + h * 64;
      short8 b0 = *(const short8*)&Kt[kb + g * 8];
      short8 b1 = *(const short8*)&Kt[kb + 32 + g * 8];
      sf[fn] = mfma16(qf[0], b0, sf[fn]);
      sf[fn] = mfma16(qf[1], b1, sf[fn]);
    }
    float tmax[4];
#pragma unroll
    for (int r = 0; r < 4; ++r) {
      float mx = sf[0][r];
#pragma unroll
      for (int fn = 1; fn < 8; ++fn) mx = fmaxf(mx, sf[fn][r]);
      tmax[r] = mx;
    }
#pragma unroll
    for (int m = 1; m <= 8; m <<= 1)
#pragma unroll
      for (int r = 0; r < 4; ++r) tmax[r] = fmaxf(tmax[r], __shfl_xor(tmax[r], m));
    float mnew[4], alpha[4], tsum[4];
#pragma unroll
    for (int r = 0; r < 4; ++r) {
      mnew[r] = fmaxf(mrun[r], tmax[r]);
      alpha[r] = __expf(mrun[r] - mnew[r]);
      tsum[r] = 0.f;
    }
#pragma unroll
    for (int fn = 0; fn < 8; ++fn)
#pragma unroll
      for (int r = 0; r < 4; ++r) {
        float p = __expf(sf[fn][r] - mnew[r]);
        sf[fn][r] = p;
        tsum[r] += p;
      }
#pragma unroll
    for (int m = 1; m <= 8; m <<= 1)
#pragma unroll
      for (int r = 0; r < 4; ++r) tsum[r] += __shfl_xor(tsum[r], m);
#pragma unroll
    for (int r = 0; r < 4; ++r) {
      srun[r] = srun[r] * alpha[r] + tsum[r];
      mrun[r] = mnew[r];
    }
#pragma unroll
    for (int fd = 0; fd < 4; ++fd)
#pragma unroll
      for (int r = 0; r < 4; ++r) oacc[fd][r] *= alpha[r];
    // store P (bf16) to this wave's private LDS strip, re-read in A-operand layout
#pragma unroll
    for (int fn = 0; fn < 8; ++fn)
#pragma unroll
      for (int r = 0; r < 4; ++r) p_sm[w][g * 4 + r][fn * 16 + c16] = f2bf(sf[fn][r]);
#pragma unroll
    for (int kk = 0; kk < 4; ++kk) {
      short8 pa = *(const short8*)&p_sm[w][c16][kk * 32 + g * 8];
#pragma unroll
      for (int fd = 0; fd < 4; ++fd) {
        short8 vb = *(const short8*)&Vb[(size_t)(h * 64 + fd * 16 + c16) * NN + m0 + kk * 32 + g * 8];
        oacc[fd] = mfma16(pa, vb, oacc[fd]);
      }
    }
  }
#pragma unroll
  for (int fd = 0; fd < 4; ++fd)
#pragma unroll
    for (int r = 0; r < 4; ++r) {
      int l = l0 + g * 4 + r;
      Out[(size_t)h * (NN * DH) + (size_t)l * DH + fd * 16 + c16] = oacc[fd][r] / srun[r];
    }
}

// ---------------------------------------------------------------- launch
extern "C" void kernel_launch(void* const* d_in, const int* in_sizes, int n_in,
                              void* d_out, int out_size, void* d_ws, size_t ws_size,
                              hipStream_t stream) {
  const float* x = (const float*)d_in[0];
  const int* ei = (const int*)d_in[1];
  // d_in[2] edge_attr: unused by the reference
  const float* Wg = (const float*)d_in[3];
  const float* ln1g = (const float*)d_in[4];
  const float* ln1b = (const float*)d_in[5];
  const float* Wq = (const float*)d_in[6];
  const float* bq = (const float*)d_in[7];
  const float* Wk = (const float*)d_in[8];
  const float* bk = (const float*)d_in[9];
  const float* Wv = (const float*)d_in[10];
  const float* bv = (const float*)d_in[11];
  const float* Wo = (const float*)d_in[12];
  const float* bo = (const float*)d_in[13];
  const float* ln2g = (const float*)d_in[14];
  const float* ln2b = (const float*)d_in[15];
  float* out = (float*)d_out;

  // workspace layout (floats)
  float* ws_f = (float*)d_ws;
  float* deg = ws_f;              // 4096
  float* dinv = ws_f + 4096;      // 4096
  float* colsum = ws_f + 8192;    // 512
  float* sumsq = ws_f + 8704;     // 1 (contiguous with colsum for one memset)
  float* mu = ws_f + 8768;        // 512
  float* rnp = ws_f + 9280;       // 1
  float* h0 = ws_f + 16384;       // 2M f32 (GCN out; later attn out)
  float* h1 = h0 + (1u << 21);    // 2M f32 (scatter out; later O-proj out)
  float* h4 = h1 + (1u << 21);    // 2M f32 (post-LN1)
  unsigned short* Qb = (unsigned short*)(h4 + (1u << 21));  // 2M bf16 each
  unsigned short* Kb = Qb + (1u << 21);
  unsigned short* Vb = Kb + (1u << 21);
  unsigned short* Qt = Vb + (1u << 21);
  unsigned short* Kt = Qt + (1u << 21);
  const size_t needed = (size_t)(16384 + 3 * (1u << 21)) * 4 + (size_t)5 * (1u << 21) * 2;
  if (ws_size < needed) return;  // clean fail rather than OOB

  const float SCALE = 0.044194173824159216f;  // 1/sqrt(512)
  const size_t WSTRIDE = (size_t)DD * DD;

  hipMemsetAsync(deg, 0, 4096 * sizeof(float), stream);
  deg_k<<<EE / 256, 256, 0, stream>>>(ei, deg);
  dinv_k<<<NN / 256, 256, 0, stream>>>(deg, dinv);

  const float* xin = x;
  for (int i = 0; i < 2; ++i) {
    // GCN: h0 = xin @ W_gcn[i]
    gemm_k<false, false, false><<<dim3(8, 32), 256, 0, stream>>>(
        xin, Wg + i * WSTRIDE, nullptr, 1.f, h0, NN, DD, DD);
    hipMemsetAsync(h1, 0, (size_t)(1u << 21) * 4, stream);
    scatter_k<<<EE / 4, 256, 0, stream>>>(h0, ei, dinv, h1);
    // PairNorm stats + fused apply/residual/LN1
    hipMemsetAsync(colsum, 0, 513 * sizeof(float), stream);
    colstat_k<<<32, 256, 0, stream>>>(h1, colsum, sumsq);
    finalize_pn_k<<<1, 256, 0, stream>>>(colsum, sumsq, mu, rnp);
    rowfuse_k<true><<<NN, 256, 0, stream>>>(h1, mu, rnp, ln1g + i * DD, ln1b + i * DD, h4);
    // projections (scale folded into Q and K)
    gemm_k<true, true, true><<<dim3(8, 32), 256, 0, stream>>>(
        h4, Wq + i * WSTRIDE, bq + i * DD, SCALE, Qb, NN, DD, DD);
    gemm_k<true, true, true><<<dim3(8, 32), 256, 0, stream>>>(
        h4, Wk + i * WSTRIDE, bk + i * DD, SCALE, Kb, NN, DD, DD);
    gemm_k<true, true, true><<<dim3(8, 32), 256, 0, stream>>>(
        h4, Wv + i * WSTRIDE, bv + i * DD, 1.f, Vb, NN, DD, DD);
    transpose_pk<<<dim3(64, 8), 256, 0, stream>>>(Qb, Qt);
    transpose_pk<<<dim3(64, 8), 256, 0, stream>>>(Kb, Kt);
    // attention -> h0 (flat [H][N][DH] == [N,D])
    attn_k<<<dim3(64, 8), 256, 0, stream>>>(Qt, Kt, Vb, h0);
    // output projection -> h1
    gemm_k<true, true, false><<<dim3(8, 32), 256, 0, stream>>>(
        h0, Wo + i * WSTRIDE, bo + i * DD, 1.f, h1, NN, DD, DD);
    // LN2 -> layer output (d_out doubles as the inter-layer buffer)
    rowfuse_k<false><<<NN, 256, 0, stream>>>(h1, nullptr, nullptr, ln2g + i * DD, ln2b + i * DD, out);
    xin = out;
  }
}

// Round 4
// 941.344 us; speedup vs baseline: 4.7380x; 4.7380x over previous
//
#include <hip/hip_runtime.h>

// GNN_44942537785535 — MI355X bf16-MFMA implementation.
// N=4096, D=512, H=8, DH=64, E=131072, L=2.
// R1 change: edge scatter (f32 global atomics, 2 GB RMW traffic, ~80% of
// runtime) replaced by per-launch CSR build + block-per-node register gather.
// R2/R3: resubmission of R1 kernel (bench infra timeouts, no data).
// Attention uses the reference's raw-reshape semantics: Q/K/V [N,D] buffers are
// reinterpreted flat as [512][4096] (row p=h*64+d, col m), output written flat
// as [H][N][DH] and consumed as [N,D]. All pure index arithmetic, no data moves.
// Workspace requirement: ~45.2 MB (guarded).

#define NN 4096
#define DD 512
#define HH 8
#define DH 64
#define EE 131072

typedef float f32x2 __attribute__((ext_vector_type(2)));
typedef float f32x4 __attribute__((ext_vector_type(4)));
typedef short short8 __attribute__((ext_vector_type(8)));
typedef __bf16 bf16x8 __attribute__((ext_vector_type(8)));

static __device__ __forceinline__ unsigned short f2bf(float f) {
  unsigned u = __float_as_uint(f);
  return (unsigned short)((u + 0x7FFFu + ((u >> 16) & 1u)) >> 16);  // RNE
}

static __device__ __forceinline__ short8 pack8(f32x4 a, f32x4 b) {
  short8 s;
#pragma unroll
  for (int j = 0; j < 4; ++j) {
    s[j] = (short)f2bf(a[j]);
    s[j + 4] = (short)f2bf(b[j]);
  }
  return s;
}

static __device__ __forceinline__ f32x4 mfma16(short8 a, short8 b, f32x4 c) {
  return __builtin_amdgcn_mfma_f32_16x16x32_bf16(
      __builtin_bit_cast(bf16x8, a), __builtin_bit_cast(bf16x8, b), c, 0, 0, 0);
}

// ---------------------------------------------------------------- degree/dinv
__global__ __launch_bounds__(256) void deg_k(const int* __restrict__ ei, float* __restrict__ deg) {
  int t = blockIdx.x * 256 + threadIdx.x;
  atomicAdd(&deg[ei[EE + t]], 1.0f);  // dst-degree
}

__global__ __launch_bounds__(256) void dinv_k(const float* __restrict__ deg, float* __restrict__ dinv) {
  int t = blockIdx.x * 256 + threadIdx.x;
  float dg = deg[t];
  dinv[t] = dg > 0.f ? rsqrtf(fmaxf(dg, 1e-12f)) : 0.f;
}

// ---------------------------------------------------------------- CSR build
// Exclusive prefix scan of deg[4096] -> rowstart[4097]; cursor init = rowstart.
__global__ __launch_bounds__(256) void scan_k(const float* __restrict__ deg,
                                              int* __restrict__ rowstart,
                                              int* __restrict__ cursor) {
  __shared__ int part[256];
  const int t = threadIdx.x;
  int loc[16];
  int s = 0;
#pragma unroll
  for (int j = 0; j < 16; ++j) {
    loc[j] = s;
    s += (int)deg[t * 16 + j];
  }
  part[t] = s;
  __syncthreads();
  for (int off = 1; off < 256; off <<= 1) {
    int v = (t >= off) ? part[t - off] : 0;
    __syncthreads();
    part[t] += v;
    __syncthreads();
  }
  int base = (t > 0) ? part[t - 1] : 0;
#pragma unroll
  for (int j = 0; j < 16; ++j) {
    int rs = base + loc[j];
    rowstart[t * 16 + j] = rs;
    cursor[t * 16 + j] = rs;
  }
  if (t == 255) rowstart[4096] = part[255];
}

__global__ __launch_bounds__(256) void csr_fill_k(const int* __restrict__ ei,
                                                  const float* __restrict__ dinv,
                                                  int* __restrict__ cursor,
                                                  int* __restrict__ ecol,
                                                  float* __restrict__ ewt) {
  int e = blockIdx.x * 256 + threadIdx.x;
  int s = ei[e], d = ei[EE + e];
  int pos = atomicAdd(&cursor[d], 1);
  ecol[pos] = s;
  ewt[pos] = dinv[s] * dinv[d];
}

// ---------------------------------------------------------------- GCN aggregation (gather)
// One block per destination node; coalesced float2 row reads, register accum.
__global__ __launch_bounds__(256) void gather_k(const float* __restrict__ h0,
                                                const int* __restrict__ rowstart,
                                                const int* __restrict__ ecol,
                                                const float* __restrict__ ewt,
                                                float* __restrict__ h1) {
  __shared__ int s_col[256];
  __shared__ float s_w[256];
  const int node = blockIdx.x, t = threadIdx.x;
  const int beg = rowstart[node], end = rowstart[node + 1];
  f32x2 acc = {0.f, 0.f};
  for (int base = beg; base < end; base += 256) {
    int n = min(256, end - base);
    __syncthreads();
    if (t < n) {
      s_col[t] = ecol[base + t];
      s_w[t] = ewt[base + t];
    }
    __syncthreads();
    for (int j = 0; j < n; ++j) {
      int s = s_col[j];
      float en = s_w[j];
      f32x2 v = *(const f32x2*)&h0[(size_t)s * DD + 2 * t];
      acc[0] += en * v[0];
      acc[1] += en * v[1];
    }
  }
  *(f32x2*)&h1[(size_t)node * DD + 2 * t] = acc;
}

// ---------------------------------------------------------------- GEMM (bf16 MFMA)
// C[M,Nc] = A[M,K] @ (TRANS_B ? B^T : B), epilogue (acc + bias) * scale.
// Tile 128x64, 4 waves, each wave 32x64 (2x4 frags of 16x16), BK=32.
template <bool TRANS_B, bool HAS_BIAS, bool OUT_BF16>
__global__ __launch_bounds__(256) void gemm_k(const float* __restrict__ A,
                                              const float* __restrict__ B,
                                              const float* __restrict__ bias, float scale,
                                              void* __restrict__ Cv, int M, int Nc, int K) {
  __shared__ __align__(16) unsigned short a_sm[128][40];
  __shared__ __align__(16) unsigned short b_sm[64][40];
  const int tid = threadIdx.x;
  const int w = tid >> 6, lane = tid & 63, g = lane >> 4, c16 = lane & 15;
  const int m0 = blockIdx.y * 128, n0 = blockIdx.x * 64;
  const int wm = w * 32;
  f32x4 acc[2][4] = {};

  const int ar = tid >> 1, ac = (tid & 1) * 16;
  for (int k0 = 0; k0 < K; k0 += 32) {
    // issue global loads (registers) before the barrier
    const float* asrc = A + (size_t)(m0 + ar) * K + k0 + ac;
    f32x4 av0 = *(const f32x4*)(asrc + 0);
    f32x4 av1 = *(const f32x4*)(asrc + 4);
    f32x4 av2 = *(const f32x4*)(asrc + 8);
    f32x4 av3 = *(const f32x4*)(asrc + 12);
    f32x4 bv0, bv1;
    int br = 0, bc = 0, bk_ = 0, bn = 0;
    if (TRANS_B) {
      br = tid >> 2; bc = (tid & 3) * 8;
      const float* bsrc = B + (size_t)(n0 + br) * K + k0 + bc;
      bv0 = *(const f32x4*)(bsrc);
      bv1 = *(const f32x4*)(bsrc + 4);
    } else {
      bk_ = tid >> 3; bn = (tid & 7) * 8;
      const float* bsrc = B + (size_t)(k0 + bk_) * Nc + n0 + bn;
      bv0 = *(const f32x4*)(bsrc);
      bv1 = *(const f32x4*)(bsrc + 4);
    }
    __syncthreads();  // prior tile fully consumed
    *(short8*)&a_sm[ar][ac] = pack8(av0, av1);
    *(short8*)&a_sm[ar][ac + 8] = pack8(av2, av3);
    if (TRANS_B) {
      *(short8*)&b_sm[br][bc] = pack8(bv0, bv1);
    } else {
#pragma unroll
      for (int j = 0; j < 4; ++j) {
        b_sm[bn + j][bk_] = f2bf(bv0[j]);
        b_sm[bn + 4 + j][bk_] = f2bf(bv1[j]);
      }
    }
    __syncthreads();
    short8 af0 = *(const short8*)&a_sm[wm + c16][g * 8];
    short8 af1 = *(const short8*)&a_sm[wm + 16 + c16][g * 8];
#pragma unroll
    for (int fn = 0; fn < 4; ++fn) {
      short8 bf = *(const short8*)&b_sm[fn * 16 + c16][g * 8];
      acc[0][fn] = mfma16(af0, bf, acc[0][fn]);
      acc[1][fn] = mfma16(af1, bf, acc[1][fn]);
    }
  }
#pragma unroll
  for (int fm = 0; fm < 2; ++fm)
#pragma unroll
    for (int fn = 0; fn < 4; ++fn)
#pragma unroll
      for (int r = 0; r < 4; ++r) {
        int row = m0 + wm + fm * 16 + g * 4 + r;
        int col = n0 + fn * 16 + c16;
        float v = acc[fm][fn][r];
        if (HAS_BIAS) v += bias[col];
        v *= scale;
        if (OUT_BF16)
          ((unsigned short*)Cv)[(size_t)row * Nc + col] = f2bf(v);
        else
          ((float*)Cv)[(size_t)row * Nc + col] = v;
      }
}

// ---------------------------------------------------------------- PairNorm stats
__global__ __launch_bounds__(256) void colstat_k(const float* __restrict__ hin,
                                                 float* __restrict__ colsum,
                                                 float* __restrict__ sumsq) {
  const int t = threadIdx.x;
  const int r0 = blockIdx.x * 128;
  float a0 = 0.f, a1 = 0.f, sq = 0.f;
  for (int r = 0; r < 128; ++r) {
    float v0 = hin[(size_t)(r0 + r) * DD + t];
    float v1 = hin[(size_t)(r0 + r) * DD + 256 + t];
    a0 += v0; a1 += v1;
    sq += v0 * v0 + v1 * v1;
  }
  atomicAdd(&colsum[t], a0);
  atomicAdd(&colsum[t + 256], a1);
#pragma unroll
  for (int m = 1; m <= 32; m <<= 1) sq += __shfl_xor(sq, m);
  __shared__ float rr[4];
  int w = t >> 6, lane = t & 63;
  if (lane == 0) rr[w] = sq;
  __syncthreads();
  if (t == 0) atomicAdd(sumsq, rr[0] + rr[1] + rr[2] + rr[3]);
}

__global__ __launch_bounds__(256) void finalize_pn_k(const float* __restrict__ colsum,
                                                     const float* __restrict__ sumsq,
                                                     float* __restrict__ mu,
                                                     float* __restrict__ rnp) {
  const int t = threadIdx.x;
  float m0 = colsum[t] * (1.f / (float)NN);
  float m1 = colsum[t + 256] * (1.f / (float)NN);
  mu[t] = m0;
  mu[t + 256] = m1;
  float sq = m0 * m0 + m1 * m1;
#pragma unroll
  for (int m = 1; m <= 32; m <<= 1) sq += __shfl_xor(sq, m);
  __shared__ float rr[4];
  int w = t >> 6, lane = t & 63;
  if (lane == 0) rr[w] = sq;
  __syncthreads();
  if (t == 0) {
    float musq = rr[0] + rr[1] + rr[2] + rr[3];
    *rnp = rsqrtf(1e-5f + (*sumsq) * (1.f / (float)NN) - musq);
  }
}

// ---------------------------------------------------------------- fused row ops
// PN=true:  h=(hin-mu)*rn; h=relu(h)+h; LayerNorm(g,b)
// PN=false: LayerNorm(hin, g, b)
template <bool PN>
__global__ __launch_bounds__(256) void rowfuse_k(const float* __restrict__ hin,
                                                 const float* __restrict__ mu,
                                                 const float* __restrict__ rnp,
                                                 const float* __restrict__ gg,
                                                 const float* __restrict__ bb,
                                                 float* __restrict__ outp) {
  const int row = blockIdx.x, t = threadIdx.x;
  const size_t base = (size_t)row * DD;
  float v0 = hin[base + t], v1 = hin[base + 256 + t];
  if (PN) {
    float rn = *rnp;
    v0 = (v0 - mu[t]) * rn;
    v1 = (v1 - mu[t + 256]) * rn;
    v0 = fmaxf(v0, 0.f) + v0;
    v1 = fmaxf(v1, 0.f) + v1;
  }
  float s1 = v0 + v1, s2 = v0 * v0 + v1 * v1;
#pragma unroll
  for (int m = 1; m <= 32; m <<= 1) {
    s1 += __shfl_xor(s1, m);
    s2 += __shfl_xor(s2, m);
  }
  __shared__ float r1[4], r2[4];
  int w = t >> 6, lane = t & 63;
  if (lane == 0) { r1[w] = s1; r2[w] = s2; }
  __syncthreads();
  s1 = r1[0] + r1[1] + r1[2] + r1[3];
  s2 = r2[0] + r2[1] + r2[2] + r2[3];
  float mean = s1 * (1.f / (float)DD);
  float var = s2 * (1.f / (float)DD) - mean * mean;
  float inv = rsqrtf(var + 1e-5f);
  outp[base + t] = (v0 - mean) * inv * gg[t] + bb[t];
  outp[base + 256 + t] = (v1 - mean) * inv * gg[t + 256] + bb[t + 256];
}

// ---------------------------------------------------------------- [512][4096] -> [4096][512] bf16 transpose
__global__ __launch_bounds__(256) void transpose_pk(const unsigned short* __restrict__ in,
                                                    unsigned short* __restrict__ out) {
  __shared__ __align__(16) unsigned short sm[64][72];
  const int m0 = blockIdx.x * 64, p0 = blockIdx.y * 64;
  const int t = threadIdx.x;
  const int r = t >> 2, q = (t & 3) * 16;
  *(short8*)&sm[r][q] = *(const short8*)&in[(size_t)(p0 + r) * NN + m0 + q];
  *(short8*)&sm[r][q + 8] = *(const short8*)&in[(size_t)(p0 + r) * NN + m0 + q + 8];
  __syncthreads();
  short8 s0, s1;
#pragma unroll
  for (int j = 0; j < 8; ++j) {
    s0[j] = (short)sm[q + j][r];
    s1[j] = (short)sm[q + 8 + j][r];
  }
  *(short8*)&out[(size_t)(m0 + r) * DD + p0 + q] = s0;
  *(short8*)&out[(size_t)(m0 + r) * DD + p0 + q + 8] = s1;
}

// ---------------------------------------------------------------- flash attention (scrambled-view heads)
// Qt/Kt: [4096][512] bf16 (row m/l, col p=h*64+d). Vb: flat [512][4096] view.
// Out: f32 written at flat [h][l][d] (= [N,D] reinterpretation).
// Grid (64, 8); block 256 = 4 independent waves; wave handles 16 l-rows.
__global__ __launch_bounds__(256) void attn_k(const unsigned short* __restrict__ Qt,
                                              const unsigned short* __restrict__ Kt,
                                              const unsigned short* __restrict__ Vb,
                                              float* __restrict__ Out) {
  __shared__ __align__(16) unsigned short p_sm[4][16][136];
  const int tid = threadIdx.x, w = tid >> 6, lane = tid & 63;
  const int g = lane >> 4, c16 = lane & 15;
  const int h = blockIdx.y;
  const int l0 = blockIdx.x * 64 + w * 16;

  short8 qf[2];
  qf[0] = *(const short8*)&Qt[(size_t)(l0 + c16) * DD + h * 64 + g * 8];
  qf[1] = *(const short8*)&Qt[(size_t)(l0 + c16) * DD + h * 64 + 32 + g * 8];

  float mrun[4], srun[4];
  f32x4 oacc[4] = {};
#pragma unroll
  for (int r = 0; r < 4; ++r) { mrun[r] = -1e30f; srun[r] = 0.f; }

  for (int m0 = 0; m0 < NN; m0 += 128) {
    f32x4 sf[8] = {};
#pragma unroll
    for (int fn = 0; fn < 8; ++fn) {
      const size_t kb = (size_t)(m0 + fn * 16 + c16) * DD + h * 64;
      short8 b0 = *(const short8*)&Kt[kb + g * 8];
      short8 b1 = *(const short8*)&Kt[kb + 32 + g * 8];
      sf[fn] = mfma16(qf[0], b0, sf[fn]);
      sf[fn] = mfma16(qf[1], b1, sf[fn]);
    }
    float tmax[4];
#pragma unroll
    for (int r = 0; r < 4; ++r) {
      float mx = sf[0][r];
#pragma unroll
      for (int fn = 1; fn < 8; ++fn) mx = fmaxf(mx, sf[fn][r]);
      tmax[r] = mx;
    }
#pragma unroll
    for (int m = 1; m <= 8; m <<= 1)
#pragma unroll
      for (int r = 0; r < 4; ++r) tmax[r] = fmaxf(tmax[r], __shfl_xor(tmax[r], m));
    float mnew[4], alpha[4], tsum[4];
#pragma unroll
    for (int r = 0; r < 4; ++r) {
      mnew[r] = fmaxf(mrun[r], tmax[r]);
      alpha[r] = __expf(mrun[r] - mnew[r]);
      tsum[r] = 0.f;
    }
#pragma unroll
    for (int fn = 0; fn < 8; ++fn)
#pragma unroll
      for (int r = 0; r < 4; ++r) {
        float p = __expf(sf[fn][r] - mnew[r]);
        sf[fn][r] = p;
        tsum[r] += p;
      }
#pragma unroll
    for (int m = 1; m <= 8; m <<= 1)
#pragma unroll
      for (int r = 0; r < 4; ++r) tsum[r] += __shfl_xor(tsum[r], m);
#pragma unroll
    for (int r = 0; r < 4; ++r) {
      srun[r] = srun[r] * alpha[r] + tsum[r];
      mrun[r] = mnew[r];
    }
#pragma unroll
    for (int fd = 0; fd < 4; ++fd)
#pragma unroll
      for (int r = 0; r < 4; ++r) oacc[fd][r] *= alpha[r];
    // store P (bf16) to this wave's private LDS strip, re-read in A-operand layout
#pragma unroll
    for (int fn = 0; fn < 8; ++fn)
#pragma unroll
      for (int r = 0; r < 4; ++r) p_sm[w][g * 4 + r][fn * 16 + c16] = f2bf(sf[fn][r]);
#pragma unroll
    for (int kk = 0; kk < 4; ++kk) {
      short8 pa = *(const short8*)&p_sm[w][c16][kk * 32 + g * 8];
#pragma unroll
      for (int fd = 0; fd < 4; ++fd) {
        short8 vb = *(const short8*)&Vb[(size_t)(h * 64 + fd * 16 + c16) * NN + m0 + kk * 32 + g * 8];
        oacc[fd] = mfma16(pa, vb, oacc[fd]);
      }
    }
  }
#pragma unroll
  for (int fd = 0; fd < 4; ++fd)
#pragma unroll
    for (int r = 0; r < 4; ++r) {
      int l = l0 + g * 4 + r;
      Out[(size_t)h * (NN * DH) + (size_t)l * DH + fd * 16 + c16] = oacc[fd][r] / srun[r];
    }
}

// ---------------------------------------------------------------- launch
extern "C" void kernel_launch(void* const* d_in, const int* in_sizes, int n_in,
                              void* d_out, int out_size, void* d_ws, size_t ws_size,
                              hipStream_t stream) {
  const float* x = (const float*)d_in[0];
  const int* ei = (const int*)d_in[1];
  // d_in[2] edge_attr: unused by the reference
  const float* Wg = (const float*)d_in[3];
  const float* ln1g = (const float*)d_in[4];
  const float* ln1b = (const float*)d_in[5];
  const float* Wq = (const float*)d_in[6];
  const float* bq = (const float*)d_in[7];
  const float* Wk = (const float*)d_in[8];
  const float* bk = (const float*)d_in[9];
  const float* Wv = (const float*)d_in[10];
  const float* bv = (const float*)d_in[11];
  const float* Wo = (const float*)d_in[12];
  const float* bo = (const float*)d_in[13];
  const float* ln2g = (const float*)d_in[14];
  const float* ln2b = (const float*)d_in[15];
  float* out = (float*)d_out;

  // workspace layout (floats)
  float* ws_f = (float*)d_ws;
  float* deg = ws_f;              // 4096
  float* dinv = ws_f + 4096;      // 4096
  float* colsum = ws_f + 8192;    // 512
  float* sumsq = ws_f + 8704;     // 1 (contiguous with colsum for one memset)
  float* mu = ws_f + 8768;        // 512
  float* rnp = ws_f + 9280;       // 1
  float* h0 = ws_f + 16384;       // 2M f32 (GCN out; later attn out)
  float* h1 = h0 + (1u << 21);    // 2M f32 (gather out; later O-proj out)
  float* h4 = h1 + (1u << 21);    // 2M f32 (post-LN1)
  unsigned short* Qb = (unsigned short*)(h4 + (1u << 21));  // 2M bf16 each
  unsigned short* Kb = Qb + (1u << 21);
  unsigned short* Vb = Kb + (1u << 21);
  unsigned short* Qt = Vb + (1u << 21);
  unsigned short* Kt = Qt + (1u << 21);
  int* rowstart = (int*)(Kt + (1u << 21));  // 4097
  int* cursor = rowstart + 4104;            // 4096
  int* ecol = cursor + 4096;                // E
  float* ewt = (float*)(ecol + EE);         // E
  const size_t needed = (size_t)(16384 + 3 * (1u << 21)) * 4 + (size_t)5 * (1u << 21) * 2 +
                        (size_t)(4104 + 4096 + 2 * EE) * 4;
  if (ws_size < needed) return;  // clean fail rather than OOB

  const float SCALE = 0.044194173824159216f;  // 1/sqrt(512)
  const size_t WSTRIDE = (size_t)DD * DD;

  hipMemsetAsync(deg, 0, 4096 * sizeof(float), stream);
  deg_k<<<EE / 256, 256, 0, stream>>>(ei, deg);
  dinv_k<<<NN / 256, 256, 0, stream>>>(deg, dinv);
  scan_k<<<1, 256, 0, stream>>>(deg, rowstart, cursor);
  csr_fill_k<<<EE / 256, 256, 0, stream>>>(ei, dinv, cursor, ecol, ewt);

  const float* xin = x;
  for (int i = 0; i < 2; ++i) {
    // GCN: h0 = xin @ W_gcn[i]
    gemm_k<false, false, false><<<dim3(8, 32), 256, 0, stream>>>(
        xin, Wg + i * WSTRIDE, nullptr, 1.f, h0, NN, DD, DD);
    // aggregation: h1[dst] = sum_in en * h0[src]  (CSR gather, no atomics)
    gather_k<<<NN, 256, 0, stream>>>(h0, rowstart, ecol, ewt, h1);
    // PairNorm stats + fused apply/residual/LN1
    hipMemsetAsync(colsum, 0, 513 * sizeof(float), stream);
    colstat_k<<<32, 256, 0, stream>>>(h1, colsum, sumsq);
    finalize_pn_k<<<1, 256, 0, stream>>>(colsum, sumsq, mu, rnp);
    rowfuse_k<true><<<NN, 256, 0, stream>>>(h1, mu, rnp, ln1g + i * DD, ln1b + i * DD, h4);
    // projections (scale folded into Q and K)
    gemm_k<true, true, true><<<dim3(8, 32), 256, 0, stream>>>(
        h4, Wq + i * WSTRIDE, bq + i * DD, SCALE, Qb, NN, DD, DD);
    gemm_k<true, true, true><<<dim3(8, 32), 256, 0, stream>>>(
        h4, Wk + i * WSTRIDE, bk + i * DD, SCALE, Kb, NN, DD, DD);
    gemm_k<true, true, true><<<dim3(8, 32), 256, 0, stream>>>(
        h4, Wv + i * WSTRIDE, bv + i * DD, 1.f, Vb, NN, DD, DD);
    transpose_pk<<<dim3(64, 8), 256, 0, stream>>>(Qb, Qt);
    transpose_pk<<<dim3(64, 8), 256, 0, stream>>>(Kb, Kt);
    // attention -> h0 (flat [H][N][DH] == [N,D])
    attn_k<<<dim3(64, 8), 256, 0, stream>>>(Qt, Kt, Vb, h0);
    // output projection -> h1
    gemm_k<true, true, false><<<dim3(8, 32), 256, 0, stream>>>(
        h0, Wo + i * WSTRIDE, bo + i * DD, 1.f, h1, NN, DD, DD);
    // LN2 -> layer output (d_out doubles as the inter-layer buffer)
    rowfuse_k<false><<<NN, 256, 0, stream>>>(h1, nullptr, nullptr, ln2g + i * DD, ln2b + i * DD, out);
    xin = out;
  }
}

// Round 6
// 627.449 us; speedup vs baseline: 7.1083x; 1.5003x over previous
//
#include <hip/hip_runtime.h>

// GNN_44942537785535 — MI355X bf16-MFMA implementation.
// N=4096, D=512, H=8, DH=64, E=131072, L=2.
// R1: CSR gather replaces atomic scatter (4460 -> 941 us).
// R5 FAILED: counted-vmcnt pipeline raced (gload issue order not guaranteed).
// R6: attn on the proven one-barrier m97 template: K AND V double-buffered,
// prefetch t+1 at loop top, single __syncthreads per iter (full drain = safe).
// Keeps LDS XOR-swizzled staging, defer-max softmax (exact), split-K=2.
// Workspace requirement: ~45.7 MB (guarded).

#define NN 4096
#define DD 512
#define HH 8
#define DH 64
#define EE 131072

typedef float f32x2 __attribute__((ext_vector_type(2)));
typedef float f32x4 __attribute__((ext_vector_type(4)));
typedef short short8 __attribute__((ext_vector_type(8)));
typedef __bf16 bf16x8 __attribute__((ext_vector_type(8)));

static __device__ __forceinline__ unsigned short f2bf(float f) {
  unsigned u = __float_as_uint(f);
  return (unsigned short)((u + 0x7FFFu + ((u >> 16) & 1u)) >> 16);  // RNE
}

static __device__ __forceinline__ short8 pack8(f32x4 a, f32x4 b) {
  short8 s;
#pragma unroll
  for (int j = 0; j < 4; ++j) {
    s[j] = (short)f2bf(a[j]);
    s[j + 4] = (short)f2bf(b[j]);
  }
  return s;
}

static __device__ __forceinline__ f32x4 mfma16(short8 a, short8 b, f32x4 c) {
  return __builtin_amdgcn_mfma_f32_16x16x32_bf16(
      __builtin_bit_cast(bf16x8, a), __builtin_bit_cast(bf16x8, b), c, 0, 0, 0);
}

static __device__ __forceinline__ void gload16(const unsigned short* g, unsigned short* l) {
  __builtin_amdgcn_global_load_lds((const __attribute__((address_space(1))) unsigned int*)g,
                                   (__attribute__((address_space(3))) unsigned int*)l, 16, 0, 0);
}

// ---------------------------------------------------------------- degree/dinv
__global__ __launch_bounds__(256) void deg_k(const int* __restrict__ ei, float* __restrict__ deg) {
  int t = blockIdx.x * 256 + threadIdx.x;
  atomicAdd(&deg[ei[EE + t]], 1.0f);  // dst-degree
}

__global__ __launch_bounds__(256) void dinv_k(const float* __restrict__ deg, float* __restrict__ dinv) {
  int t = blockIdx.x * 256 + threadIdx.x;
  float dg = deg[t];
  dinv[t] = dg > 0.f ? rsqrtf(fmaxf(dg, 1e-12f)) : 0.f;
}

// ---------------------------------------------------------------- CSR build
__global__ __launch_bounds__(256) void scan_k(const float* __restrict__ deg,
                                              int* __restrict__ rowstart,
                                              int* __restrict__ cursor) {
  __shared__ int part[256];
  const int t = threadIdx.x;
  int loc[16];
  int s = 0;
#pragma unroll
  for (int j = 0; j < 16; ++j) {
    loc[j] = s;
    s += (int)deg[t * 16 + j];
  }
  part[t] = s;
  __syncthreads();
  for (int off = 1; off < 256; off <<= 1) {
    int v = (t >= off) ? part[t - off] : 0;
    __syncthreads();
    part[t] += v;
    __syncthreads();
  }
  int base = (t > 0) ? part[t - 1] : 0;
#pragma unroll
  for (int j = 0; j < 16; ++j) {
    int rs = base + loc[j];
    rowstart[t * 16 + j] = rs;
    cursor[t * 16 + j] = rs;
  }
  if (t == 255) rowstart[4096] = part[255];
}

__global__ __launch_bounds__(256) void csr_fill_k(const int* __restrict__ ei,
                                                  const float* __restrict__ dinv,
                                                  int* __restrict__ cursor,
                                                  int* __restrict__ ecol,
                                                  float* __restrict__ ewt) {
  int e = blockIdx.x * 256 + threadIdx.x;
  int s = ei[e], d = ei[EE + e];
  int pos = atomicAdd(&cursor[d], 1);
  ecol[pos] = s;
  ewt[pos] = dinv[s] * dinv[d];
}

// ---------------------------------------------------------------- GCN aggregation (gather)
__global__ __launch_bounds__(256) void gather_k(const float* __restrict__ h0,
                                                const int* __restrict__ rowstart,
                                                const int* __restrict__ ecol,
                                                const float* __restrict__ ewt,
                                                float* __restrict__ h1) {
  __shared__ int s_col[256];
  __shared__ float s_w[256];
  const int node = blockIdx.x, t = threadIdx.x;
  const int beg = rowstart[node], end = rowstart[node + 1];
  f32x2 acc = {0.f, 0.f};
  for (int base = beg; base < end; base += 256) {
    int n = min(256, end - base);
    __syncthreads();
    if (t < n) {
      s_col[t] = ecol[base + t];
      s_w[t] = ewt[base + t];
    }
    __syncthreads();
    for (int j = 0; j < n; ++j) {
      int s = s_col[j];
      float en = s_w[j];
      f32x2 v = *(const f32x2*)&h0[(size_t)s * DD + 2 * t];
      acc[0] += en * v[0];
      acc[1] += en * v[1];
    }
  }
  *(f32x2*)&h1[(size_t)node * DD + 2 * t] = acc;
}

// ---------------------------------------------------------------- GEMM (bf16 MFMA)
template <bool TRANS_B, bool HAS_BIAS, bool OUT_BF16>
__global__ __launch_bounds__(256) void gemm_k(const float* __restrict__ A,
                                              const float* __restrict__ B,
                                              const float* __restrict__ bias, float scale,
                                              void* __restrict__ Cv, int M, int Nc, int K) {
  __shared__ __align__(16) unsigned short a_sm[128][40];
  __shared__ __align__(16) unsigned short b_sm[64][40];
  const int tid = threadIdx.x;
  const int w = tid >> 6, lane = tid & 63, g = lane >> 4, c16 = lane & 15;
  const int m0 = blockIdx.y * 128, n0 = blockIdx.x * 64;
  const int wm = w * 32;
  f32x4 acc[2][4] = {};

  const int ar = tid >> 1, ac = (tid & 1) * 16;
  for (int k0 = 0; k0 < K; k0 += 32) {
    const float* asrc = A + (size_t)(m0 + ar) * K + k0 + ac;
    f32x4 av0 = *(const f32x4*)(asrc + 0);
    f32x4 av1 = *(const f32x4*)(asrc + 4);
    f32x4 av2 = *(const f32x4*)(asrc + 8);
    f32x4 av3 = *(const f32x4*)(asrc + 12);
    f32x4 bv0, bv1;
    int br = 0, bc = 0, bk_ = 0, bn = 0;
    if (TRANS_B) {
      br = tid >> 2; bc = (tid & 3) * 8;
      const float* bsrc = B + (size_t)(n0 + br) * K + k0 + bc;
      bv0 = *(const f32x4*)(bsrc);
      bv1 = *(const f32x4*)(bsrc + 4);
    } else {
      bk_ = tid >> 3; bn = (tid & 7) * 8;
      const float* bsrc = B + (size_t)(k0 + bk_) * Nc + n0 + bn;
      bv0 = *(const f32x4*)(bsrc);
      bv1 = *(const f32x4*)(bsrc + 4);
    }
    __syncthreads();
    *(short8*)&a_sm[ar][ac] = pack8(av0, av1);
    *(short8*)&a_sm[ar][ac + 8] = pack8(av2, av3);
    if (TRANS_B) {
      *(short8*)&b_sm[br][bc] = pack8(bv0, bv1);
    } else {
#pragma unroll
      for (int j = 0; j < 4; ++j) {
        b_sm[bn + j][bk_] = f2bf(bv0[j]);
        b_sm[bn + 4 + j][bk_] = f2bf(bv1[j]);
      }
    }
    __syncthreads();
    short8 af0 = *(const short8*)&a_sm[wm + c16][g * 8];
    short8 af1 = *(const short8*)&a_sm[wm + 16 + c16][g * 8];
#pragma unroll
    for (int fn = 0; fn < 4; ++fn) {
      short8 bf = *(const short8*)&b_sm[fn * 16 + c16][g * 8];
      acc[0][fn] = mfma16(af0, bf, acc[0][fn]);
      acc[1][fn] = mfma16(af1, bf, acc[1][fn]);
    }
  }
#pragma unroll
  for (int fm = 0; fm < 2; ++fm)
#pragma unroll
    for (int fn = 0; fn < 4; ++fn)
#pragma unroll
      for (int r = 0; r < 4; ++r) {
        int row = m0 + wm + fm * 16 + g * 4 + r;
        int col = n0 + fn * 16 + c16;
        float v = acc[fm][fn][r];
        if (HAS_BIAS) v += bias[col];
        v *= scale;
        if (OUT_BF16)
          ((unsigned short*)Cv)[(size_t)row * Nc + col] = f2bf(v);
        else
          ((float*)Cv)[(size_t)row * Nc + col] = v;
      }
}

// ---------------------------------------------------------------- PairNorm stats
__global__ __launch_bounds__(256) void colstat_k(const float* __restrict__ hin,
                                                 float* __restrict__ colsum,
                                                 float* __restrict__ sumsq) {
  const int t = threadIdx.x;
  const int r0 = blockIdx.x * 128;
  float a0 = 0.f, a1 = 0.f, sq = 0.f;
  for (int r = 0; r < 128; ++r) {
    float v0 = hin[(size_t)(r0 + r) * DD + t];
    float v1 = hin[(size_t)(r0 + r) * DD + 256 + t];
    a0 += v0; a1 += v1;
    sq += v0 * v0 + v1 * v1;
  }
  atomicAdd(&colsum[t], a0);
  atomicAdd(&colsum[t + 256], a1);
#pragma unroll
  for (int m = 1; m <= 32; m <<= 1) sq += __shfl_xor(sq, m);
  __shared__ float rr[4];
  int w = t >> 6, lane = t & 63;
  if (lane == 0) rr[w] = sq;
  __syncthreads();
  if (t == 0) atomicAdd(sumsq, rr[0] + rr[1] + rr[2] + rr[3]);
}

__global__ __launch_bounds__(256) void finalize_pn_k(const float* __restrict__ colsum,
                                                     const float* __restrict__ sumsq,
                                                     float* __restrict__ mu,
                                                     float* __restrict__ rnp) {
  const int t = threadIdx.x;
  float m0 = colsum[t] * (1.f / (float)NN);
  float m1 = colsum[t + 256] * (1.f / (float)NN);
  mu[t] = m0;
  mu[t + 256] = m1;
  float sq = m0 * m0 + m1 * m1;
#pragma unroll
  for (int m = 1; m <= 32; m <<= 1) sq += __shfl_xor(sq, m);
  __shared__ float rr[4];
  int w = t >> 6, lane = t & 63;
  if (lane == 0) rr[w] = sq;
  __syncthreads();
  if (t == 0) {
    float musq = rr[0] + rr[1] + rr[2] + rr[3];
    *rnp = rsqrtf(1e-5f + (*sumsq) * (1.f / (float)NN) - musq);
  }
}

// ---------------------------------------------------------------- fused row ops
template <bool PN>
__global__ __launch_bounds__(256) void rowfuse_k(const float* __restrict__ hin,
                                                 const float* __restrict__ mu,
                                                 const float* __restrict__ rnp,
                                                 const float* __restrict__ gg,
                                                 const float* __restrict__ bb,
                                                 float* __restrict__ outp) {
  const int row = blockIdx.x, t = threadIdx.x;
  const size_t base = (size_t)row * DD;
  float v0 = hin[base + t], v1 = hin[base + 256 + t];
  if (PN) {
    float rn = *rnp;
    v0 = (v0 - mu[t]) * rn;
    v1 = (v1 - mu[t + 256]) * rn;
    v0 = fmaxf(v0, 0.f) + v0;
    v1 = fmaxf(v1, 0.f) + v1;
  }
  float s1 = v0 + v1, s2 = v0 * v0 + v1 * v1;
#pragma unroll
  for (int m = 1; m <= 32; m <<= 1) {
    s1 += __shfl_xor(s1, m);
    s2 += __shfl_xor(s2, m);
  }
  __shared__ float r1[4], r2[4];
  int w = t >> 6, lane = t & 63;
  if (lane == 0) { r1[w] = s1; r2[w] = s2; }
  __syncthreads();
  s1 = r1[0] + r1[1] + r1[2] + r1[3];
  s2 = r2[0] + r2[1] + r2[2] + r2[3];
  float mean = s1 * (1.f / (float)DD);
  float var = s2 * (1.f / (float)DD) - mean * mean;
  float inv = rsqrtf(var + 1e-5f);
  outp[base + t] = (v0 - mean) * inv * gg[t] + bb[t];
  outp[base + 256 + t] = (v1 - mean) * inv * gg[t + 256] + bb[t + 256];
}

// ---------------------------------------------------------------- [512][4096] -> [4096][512] bf16 transpose
__global__ __launch_bounds__(256) void transpose_pk(const unsigned short* __restrict__ in,
                                                    unsigned short* __restrict__ out) {
  __shared__ __align__(16) unsigned short sm[64][72];
  const int m0 = blockIdx.x * 64, p0 = blockIdx.y * 64;
  const int t = threadIdx.x;
  const int r = t >> 2, q = (t & 3) * 16;
  *(short8*)&sm[r][q] = *(const short8*)&in[(size_t)(p0 + r) * NN + m0 + q];
  *(short8*)&sm[r][q + 8] = *(const short8*)&in[(size_t)(p0 + r) * NN + m0 + q + 8];
  __syncthreads();
  short8 s0, s1;
#pragma unroll
  for (int j = 0; j < 8; ++j) {
    s0[j] = (short)sm[q + j][r];
    s1[j] = (short)sm[q + 8 + j][r];
  }
  *(short8*)&out[(size_t)(m0 + r) * DD + p0 + q] = s0;
  *(short8*)&out[(size_t)(m0 + r) * DD + p0 + q + 8] = s1;
}

// ---------------------------------------------------------------- flash attention, split-K
// Qt/Kt: [4096][512] bf16 (row m/l, col p=h*64+d). Vb: flat [512][4096] view.
// grid (64, 8, 2). Block = 4 waves, wave owns 16 l-rows. K AND V tiles
// double-buffered in LDS (XOR-swizzled via pre-swizzled global source);
// prefetch t+1 at loop top; ONE __syncthreads per iter (full drain = the
// m97-verified overlap pattern, no issue-order sensitivity).
// Partial output (unnormalized) -> Op[z]; (M, srun) -> ms. Merged after.
__global__ __launch_bounds__(256, 4) void attn_k(const unsigned short* __restrict__ Qt,
                                                 const unsigned short* __restrict__ Kt,
                                                 const unsigned short* __restrict__ Vb,
                                                 float* __restrict__ Op0,
                                                 float* __restrict__ Op1,
                                                 float* __restrict__ ms) {
  __shared__ __align__(16) unsigned short k_sm[2][64][64];  // 16 KB
  __shared__ __align__(16) unsigned short v_sm[2][64][64];  // 16 KB
  __shared__ __align__(16) unsigned short p_sm[4][16][64];  // 8 KB  (total 40 KB = 4 blk/CU)
  const int tid = threadIdx.x, w = tid >> 6, lane = tid & 63;
  const int g = lane >> 4, c16 = lane & 15;
  const int h = blockIdx.y, z = blockIdx.z;
  const int zbase = z * (NN / 2);
  const int l0 = blockIdx.x * 64 + w * 16;
  float* __restrict__ Op = z ? Op1 : Op0;

  // Q fragments (A-operand): row l0+c16, dims h*64 + [0..64)
  short8 qf0 = *(const short8*)&Qt[(size_t)(l0 + c16) * DD + h * 64 + g * 8];
  short8 qf1 = *(const short8*)&Qt[(size_t)(l0 + c16) * DD + h * 64 + 32 + g * 8];

  // staging: linear LDS dest (wave-uniform base + lane*16B), global source
  // column pre-XOR'd so LDS[row][b] = global[row][b ^ ((row&7)<<4)]
  const int srow = lane >> 3, cg = lane & 7;
  const int swz = ((cg * 16) ^ (srow << 4)) >> 1;  // short offset within 128B row
  const unsigned short* kgbase = Kt + (size_t)(zbase + w * 16 + srow) * DD + h * 64 + swz;
  const unsigned short* vgbase = Vb + (size_t)(h * 64 + w * 16 + srow) * NN + zbase + swz;

  // prologue: stage tile 0 into buffer 0
  gload16(kgbase, &k_sm[0][w * 16][0]);
  gload16(kgbase + (size_t)8 * DD, &k_sm[0][w * 16 + 8][0]);
  gload16(vgbase, &v_sm[0][w * 16][0]);
  gload16(vgbase + (size_t)8 * NN, &v_sm[0][w * 16 + 8][0]);
  __syncthreads();

  float M = 0.f;
  float srun[4] = {0.f, 0.f, 0.f, 0.f};
  f32x4 oacc[4] = {};
  const int sx = (c16 & 7) << 4;

  for (int t = 0; t < 32; ++t) {
    const int cb = t & 1;
    if (t < 31) {  // prefetch next tile into the other buffer (drained at barrier)
      const size_t ko = (size_t)(t + 1) * 64 * DD;
      gload16(kgbase + ko, &k_sm[cb ^ 1][w * 16][0]);
      gload16(kgbase + ko + (size_t)8 * DD, &k_sm[cb ^ 1][w * 16 + 8][0]);
      gload16(vgbase + (t + 1) * 64, &v_sm[cb ^ 1][w * 16][0]);
      gload16(vgbase + (t + 1) * 64 + (size_t)8 * NN, &v_sm[cb ^ 1][w * 16 + 8][0]);
    }
    // QK^T for 64 keys
    f32x4 sf[4] = {};
#pragma unroll
    for (int fn = 0; fn < 4; ++fn) {
      const char* kr = (const char*)&k_sm[cb][fn * 16 + c16][0];
      short8 b0 = *(const short8*)(kr + ((g * 16) ^ sx));
      short8 b1 = *(const short8*)(kr + ((64 + g * 16) ^ sx));
      sf[fn] = mfma16(qf0, b0, sf[fn]);
      sf[fn] = mfma16(qf1, b1, sf[fn]);
    }
    // defer-max softmax: speculative exp against wave-uniform M, exact rare fixup
    float a0 = fmaxf(fmaxf(sf[0][0], sf[0][1]), fmaxf(sf[0][2], sf[0][3]));
    float a1 = fmaxf(fmaxf(sf[1][0], sf[1][1]), fmaxf(sf[1][2], sf[1][3]));
    float a2 = fmaxf(fmaxf(sf[2][0], sf[2][1]), fmaxf(sf[2][2], sf[2][3]));
    float a3 = fmaxf(fmaxf(sf[3][0], sf[3][1]), fmaxf(sf[3][2], sf[3][3]));
    float wmax = fmaxf(fmaxf(a0, a1), fmaxf(a2, a3));
#pragma unroll
    for (int m = 1; m <= 32; m <<= 1) wmax = fmaxf(wmax, __shfl_xor(wmax, m));
#pragma unroll
    for (int fn = 0; fn < 4; ++fn)
#pragma unroll
      for (int r = 0; r < 4; ++r) sf[fn][r] = __expf(sf[fn][r] - M);
    if (wmax > M + 25.f) {  // never for this data; exact fixup if it happens
      float alpha = __expf(M - wmax);
#pragma unroll
      for (int r = 0; r < 4; ++r) srun[r] *= alpha;
#pragma unroll
      for (int fd = 0; fd < 4; ++fd)
#pragma unroll
        for (int r = 0; r < 4; ++r) oacc[fd][r] *= alpha;
#pragma unroll
      for (int fn = 0; fn < 4; ++fn)
#pragma unroll
        for (int r = 0; r < 4; ++r) sf[fn][r] *= alpha;
      M = wmax;
    }
    float ts[4];
#pragma unroll
    for (int r = 0; r < 4; ++r) ts[r] = sf[0][r] + sf[1][r] + sf[2][r] + sf[3][r];
#pragma unroll
    for (int m = 1; m <= 8; m <<= 1)
#pragma unroll
      for (int r = 0; r < 4; ++r) ts[r] += __shfl_xor(ts[r], m);
#pragma unroll
    for (int r = 0; r < 4; ++r) srun[r] += ts[r];
    // P -> per-wave LDS strip (bf16, A-operand layout); same-wave RAW is
    // in-order in the LDS pipe, no cross-wave access
#pragma unroll
    for (int fn = 0; fn < 4; ++fn)
#pragma unroll
      for (int r = 0; r < 4; ++r) p_sm[w][g * 4 + r][fn * 16 + c16] = f2bf(sf[fn][r]);
    // PV
#pragma unroll
    for (int kk = 0; kk < 2; ++kk) {
      short8 pa = *(const short8*)&p_sm[w][c16][kk * 32 + g * 8];
#pragma unroll
      for (int fd = 0; fd < 4; ++fd) {
        const char* vr = (const char*)&v_sm[cb][fd * 16 + c16][0];
        short8 vbf = *(const short8*)(vr + ((kk * 64 + g * 16) ^ sx));
        oacc[fd] = mfma16(pa, vbf, oacc[fd]);
      }
    }
    __syncthreads();  // drains t+1 loads (visible next iter) + fences reads of cb
  }
  // epilogue: unnormalized partials + (M, srun)
#pragma unroll
  for (int fd = 0; fd < 4; ++fd)
#pragma unroll
    for (int r = 0; r < 4; ++r) {
      int l = l0 + g * 4 + r;
      Op[((size_t)h * NN + l) * DH + fd * 16 + c16] = oacc[fd][r];
    }
  if (c16 == 0) {
#pragma unroll
    for (int r = 0; r < 4; ++r) {
      int hl = h * NN + l0 + g * 4 + r;
      f32x2 pr = {M, srun[r]};
      *(f32x2*)&ms[((size_t)z * (HH * NN) + hl) * 2] = pr;
    }
  }
}

// merge the two split-K halves: out = (w0*O0 + w1*O1) / (w0*s0 + w1*s1)
__global__ __launch_bounds__(256) void attn_merge_k(const float* __restrict__ Op0,
                                                    const float* __restrict__ Op1,
                                                    const float* __restrict__ ms,
                                                    float* __restrict__ Out) {
  const int t = threadIdx.x;
  const int hl = blockIdx.x * 4 + (t >> 6);
  const int d = t & 63;
  float M0 = ms[(size_t)hl * 2], s0 = ms[(size_t)hl * 2 + 1];
  float M1 = ms[((size_t)(HH * NN) + hl) * 2], s1 = ms[((size_t)(HH * NN) + hl) * 2 + 1];
  float M = fmaxf(M0, M1);
  float w0 = __expf(M0 - M), w1 = __expf(M1 - M);
  float inv = 1.f / (w0 * s0 + w1 * s1);
  size_t idx = (size_t)hl * DH + d;
  Out[idx] = (w0 * Op0[idx] + w1 * Op1[idx]) * inv;
}

// ---------------------------------------------------------------- launch
extern "C" void kernel_launch(void* const* d_in, const int* in_sizes, int n_in,
                              void* d_out, int out_size, void* d_ws, size_t ws_size,
                              hipStream_t stream) {
  const float* x = (const float*)d_in[0];
  const int* ei = (const int*)d_in[1];
  const float* Wg = (const float*)d_in[3];
  const float* ln1g = (const float*)d_in[4];
  const float* ln1b = (const float*)d_in[5];
  const float* Wq = (const float*)d_in[6];
  const float* bq = (const float*)d_in[7];
  const float* Wk = (const float*)d_in[8];
  const float* bk = (const float*)d_in[9];
  const float* Wv = (const float*)d_in[10];
  const float* bv = (const float*)d_in[11];
  const float* Wo = (const float*)d_in[12];
  const float* bo = (const float*)d_in[13];
  const float* ln2g = (const float*)d_in[14];
  const float* ln2b = (const float*)d_in[15];
  float* out = (float*)d_out;

  float* ws_f = (float*)d_ws;
  float* deg = ws_f;              // 4096
  float* dinv = ws_f + 4096;      // 4096
  float* colsum = ws_f + 8192;    // 512
  float* sumsq = ws_f + 8704;     // 1
  float* mu = ws_f + 8768;        // 512
  float* rnp = ws_f + 9280;       // 1
  float* h0 = ws_f + 16384;       // 2M f32 (GCN out; later attn-merged out)
  float* h1 = h0 + (1u << 21);    // 2M f32 (gather out; attn Op0; O-proj out)
  float* h4 = h1 + (1u << 21);    // 2M f32 (post-LN1; attn Op1)
  unsigned short* Qb = (unsigned short*)(h4 + (1u << 21));  // 2M bf16 each
  unsigned short* Kb = Qb + (1u << 21);
  unsigned short* Vb = Kb + (1u << 21);
  unsigned short* Qt = Vb + (1u << 21);
  unsigned short* Kt = Qt + (1u << 21);
  int* rowstart = (int*)(Kt + (1u << 21));  // 4097
  int* cursor = rowstart + 4104;            // 4096
  int* ecol = cursor + 4096;                // E
  float* ewt = (float*)(ecol + EE);         // E
  float* msbuf = ewt + EE;                  // 2*8*4096*2 = 131072
  const size_t needed = (size_t)(16384 + 3 * (1u << 21)) * 4 + (size_t)5 * (1u << 21) * 2 +
                        (size_t)(4104 + 4096 + 2 * EE + 131072) * 4;
  if (ws_size < needed) return;  // clean fail rather than OOB

  const float SCALE = 0.044194173824159216f;  // 1/sqrt(512)
  const size_t WSTRIDE = (size_t)DD * DD;

  hipMemsetAsync(deg, 0, 4096 * sizeof(float), stream);
  deg_k<<<EE / 256, 256, 0, stream>>>(ei, deg);
  dinv_k<<<NN / 256, 256, 0, stream>>>(deg, dinv);
  scan_k<<<1, 256, 0, stream>>>(deg, rowstart, cursor);
  csr_fill_k<<<EE / 256, 256, 0, stream>>>(ei, dinv, cursor, ecol, ewt);

  const float* xin = x;
  for (int i = 0; i < 2; ++i) {
    gemm_k<false, false, false><<<dim3(8, 32), 256, 0, stream>>>(
        xin, Wg + i * WSTRIDE, nullptr, 1.f, h0, NN, DD, DD);
    gather_k<<<NN, 256, 0, stream>>>(h0, rowstart, ecol, ewt, h1);
    hipMemsetAsync(colsum, 0, 513 * sizeof(float), stream);
    colstat_k<<<32, 256, 0, stream>>>(h1, colsum, sumsq);
    finalize_pn_k<<<1, 256, 0, stream>>>(colsum, sumsq, mu, rnp);
    rowfuse_k<true><<<NN, 256, 0, stream>>>(h1, mu, rnp, ln1g + i * DD, ln1b + i * DD, h4);
    gemm_k<true, true, true><<<dim3(8, 32), 256, 0, stream>>>(
        h4, Wq + i * WSTRIDE, bq + i * DD, SCALE, Qb, NN, DD, DD);
    gemm_k<true, true, true><<<dim3(8, 32), 256, 0, stream>>>(
        h4, Wk + i * WSTRIDE, bk + i * DD, SCALE, Kb, NN, DD, DD);
    gemm_k<true, true, true><<<dim3(8, 32), 256, 0, stream>>>(
        h4, Wv + i * WSTRIDE, bv + i * DD, 1.f, Vb, NN, DD, DD);
    transpose_pk<<<dim3(64, 8), 256, 0, stream>>>(Qb, Qt);
    transpose_pk<<<dim3(64, 8), 256, 0, stream>>>(Kb, Kt);
    // attention (split-K=2): partials into h1/h4, merge into h0
    attn_k<<<dim3(64, 8, 2), 256, 0, stream>>>(Qt, Kt, Vb, h1, h4, msbuf);
    attn_merge_k<<<HH * NN / 4, 256, 0, stream>>>(h1, h4, msbuf, h0);
    gemm_k<true, true, false><<<dim3(8, 32), 256, 0, stream>>>(
        h0, Wo + i * WSTRIDE, bo + i * DD, 1.f, h1, NN, DD, DD);
    rowfuse_k<false><<<NN, 256, 0, stream>>>(h1, nullptr, nullptr, ln2g + i * DD, ln2b + i * DD, out);
    xin = out;
  }
}

// Round 9
// 457.716 us; speedup vs baseline: 9.7442x; 1.3708x over previous
//
#include <hip/hip_runtime.h>

// GNN_44942537785535 — MI355X bf16-MFMA implementation.
// N=4096, D=512, H=8, DH=64, E=131072, L=2.
// R1: CSR gather replaces atomic scatter (4460 -> 941 us).
// R6: attn m97-template rebuild + split-K=2 (941 -> 627 us).
// R7/R8/R9: (a) all GEMMs rebuilt m97-style on pre-converted bf16 weights+acts
//     (global_load_lds w16, BK=64, dbuf, XOR-swizzle via pre-swizzled source);
//     (b) gather reads bf16 (halves L2/L3 stream); (c) attn: row-sum via
//     ones-column MFMA (idle pipe) replacing 32 shuffle ops, __any overflow
//     guard replacing per-tile wave-max butterfly, bf16 partials.
//     (R8, R9 = resubmissions; infra failures, kernel never executed.)
// Workspace: ~44.7 MB (R4 proved >=47.8 available; guarded).

#define NN 4096
#define DD 512
#define HH 8
#define DH 64
#define EE 131072

typedef float f32x2 __attribute__((ext_vector_type(2)));
typedef float f32x4 __attribute__((ext_vector_type(4)));
typedef short short8 __attribute__((ext_vector_type(8)));
typedef unsigned short u16x4 __attribute__((ext_vector_type(4)));
typedef __bf16 bf16x8 __attribute__((ext_vector_type(8)));

static __device__ __forceinline__ unsigned short f2bf(float f) {
  unsigned u = __float_as_uint(f);
  return (unsigned short)((u + 0x7FFFu + ((u >> 16) & 1u)) >> 16);  // RNE
}
static __device__ __forceinline__ float bf2f(unsigned short s) {
  return __uint_as_float(((unsigned)s) << 16);
}

static __device__ __forceinline__ f32x4 mfma16(short8 a, short8 b, f32x4 c) {
  return __builtin_amdgcn_mfma_f32_16x16x32_bf16(
      __builtin_bit_cast(bf16x8, a), __builtin_bit_cast(bf16x8, b), c, 0, 0, 0);
}

static __device__ __forceinline__ void gload16(const unsigned short* g, unsigned short* l) {
  __builtin_amdgcn_global_load_lds((const __attribute__((address_space(1))) unsigned int*)g,
                                   (__attribute__((address_space(3))) unsigned int*)l, 16, 0, 0);
}

// ---------------------------------------------------------------- degree/dinv
__global__ __launch_bounds__(256) void deg_k(const int* __restrict__ ei, float* __restrict__ deg) {
  int t = blockIdx.x * 256 + threadIdx.x;
  atomicAdd(&deg[ei[EE + t]], 1.0f);
}

__global__ __launch_bounds__(256) void dinv_k(const float* __restrict__ deg, float* __restrict__ dinv) {
  int t = blockIdx.x * 256 + threadIdx.x;
  float dg = deg[t];
  dinv[t] = dg > 0.f ? rsqrtf(fmaxf(dg, 1e-12f)) : 0.f;
}

// ---------------------------------------------------------------- CSR build
__global__ __launch_bounds__(256) void scan_k(const float* __restrict__ deg,
                                              int* __restrict__ rowstart,
                                              int* __restrict__ cursor) {
  __shared__ int part[256];
  const int t = threadIdx.x;
  int loc[16];
  int s = 0;
#pragma unroll
  for (int j = 0; j < 16; ++j) {
    loc[j] = s;
    s += (int)deg[t * 16 + j];
  }
  part[t] = s;
  __syncthreads();
  for (int off = 1; off < 256; off <<= 1) {
    int v = (t >= off) ? part[t - off] : 0;
    __syncthreads();
    part[t] += v;
    __syncthreads();
  }
  int base = (t > 0) ? part[t - 1] : 0;
#pragma unroll
  for (int j = 0; j < 16; ++j) {
    int rs = base + loc[j];
    rowstart[t * 16 + j] = rs;
    cursor[t * 16 + j] = rs;
  }
  if (t == 255) rowstart[4096] = part[255];
}

__global__ __launch_bounds__(256) void csr_fill_k(const int* __restrict__ ei,
                                                  const float* __restrict__ dinv,
                                                  int* __restrict__ cursor,
                                                  int* __restrict__ ecol,
                                                  float* __restrict__ ewt) {
  int e = blockIdx.x * 256 + threadIdx.x;
  int s = ei[e], d = ei[EE + e];
  int pos = atomicAdd(&cursor[d], 1);
  ecol[pos] = s;
  ewt[pos] = dinv[s] * dinv[d];
}

// ---------------------------------------------------------------- converts
__global__ __launch_bounds__(256) void cvt_k(const float* __restrict__ s,
                                             unsigned short* __restrict__ d, int n4) {
  int i = blockIdx.x * 256 + threadIdx.x;
  if (i < n4) {
    f32x4 v = *(const f32x4*)&s[i * 4];
    u16x4 o;
#pragma unroll
    for (int j = 0; j < 4; ++j) o[j] = f2bf(v[j]);
    *(u16x4*)&d[i * 4] = o;
  }
}

// Wg [512 k][512 j] f32 -> WgT [512 j][512 k] bf16
__global__ __launch_bounds__(256) void wtr_k(const float* __restrict__ in,
                                             unsigned short* __restrict__ out) {
  __shared__ unsigned short sm[64][72];
  const int k0 = blockIdx.y * 64, j0 = blockIdx.x * 64;
  const int t = threadIdx.x;
  const int r = t >> 2, q = (t & 3) * 16;
  const float* src = in + (size_t)(k0 + r) * 512 + j0 + q;
#pragma unroll
  for (int jj = 0; jj < 16; ++jj) sm[r][q + jj] = f2bf(src[jj]);
  __syncthreads();
  short8 s0, s1;
#pragma unroll
  for (int j = 0; j < 8; ++j) {
    s0[j] = (short)sm[q + j][r];
    s1[j] = (short)sm[q + 8 + j][r];
  }
  *(short8*)&out[(size_t)(j0 + r) * 512 + k0 + q] = s0;
  *(short8*)&out[(size_t)(j0 + r) * 512 + k0 + q + 8] = s1;
}

// ---------------------------------------------------------------- GCN aggregation (bf16 in, f32 out)
__global__ __launch_bounds__(256) void gather_k(const unsigned short* __restrict__ hb,
                                                const int* __restrict__ rowstart,
                                                const int* __restrict__ ecol,
                                                const float* __restrict__ ewt,
                                                float* __restrict__ h1) {
  __shared__ int s_col[256];
  __shared__ float s_w[256];
  const int node = blockIdx.x, t = threadIdx.x;
  const int beg = rowstart[node], end = rowstart[node + 1];
  float a0 = 0.f, a1 = 0.f;
  for (int base = beg; base < end; base += 256) {
    int n = min(256, end - base);
    __syncthreads();
    if (t < n) {
      s_col[t] = ecol[base + t];
      s_w[t] = ewt[base + t];
    }
    __syncthreads();
    for (int j = 0; j < n; ++j) {
      int s = s_col[j];
      float en = s_w[j];
      unsigned v = *(const unsigned*)&hb[(size_t)s * DD + 2 * t];
      a0 += en * __uint_as_float(v << 16);
      a1 += en * __uint_as_float(v & 0xFFFF0000u);
    }
  }
  f32x2 acc = {a0, a1};
  *(f32x2*)&h1[(size_t)node * DD + 2 * t] = acc;
}

// ---------------------------------------------------------------- bf16 GEMM (m97-style)
// C[M,Nc] = A[M,K] @ B[Nc,K]^T (both bf16), epilogue (acc+bias)*scale.
// Tile 64x64, BK=64, 4 waves (each 32x32), dbuf LDS + global_load_lds w16,
// XOR-swizzled rows via pre-swizzled global source (both-sides, rule 21).
template <bool HAS_BIAS, bool OUT_BF16>
__global__ __launch_bounds__(256) void gemm_bt_k(const unsigned short* __restrict__ A,
                                                 const unsigned short* __restrict__ B,
                                                 const float* __restrict__ bias, float scale,
                                                 void* __restrict__ Cv, int M, int Nc, int K) {
  __shared__ __align__(16) unsigned short a_sm[2][64][64];
  __shared__ __align__(16) unsigned short b_sm[2][64][64];
  const int tid = threadIdx.x, w = tid >> 6, lane = tid & 63;
  const int g = lane >> 4, c16 = lane & 15;
  const int n0 = blockIdx.x * 64, m0 = blockIdx.y * 64;
  const int wm = (w >> 1) * 32, wn = (w & 1) * 32;
  const int srow = lane >> 3, cg = lane & 7;
  const int swz = ((cg * 16) ^ (srow << 4)) >> 1;  // shorts within 128B row
  const unsigned short* ag = A + (size_t)(m0 + w * 8 + srow) * K + swz;
  const unsigned short* bg = B + (size_t)(n0 + w * 8 + srow) * K + swz;
  f32x4 acc[2][2] = {};

  gload16(ag, &a_sm[0][w * 8][0]);
  gload16(ag + (size_t)32 * K, &a_sm[0][w * 8 + 32][0]);
  gload16(bg, &b_sm[0][w * 8][0]);
  gload16(bg + (size_t)32 * K, &b_sm[0][w * 8 + 32][0]);
  __syncthreads();

  const int rx = (c16 & 7) << 4;  // read-side XOR (bytes)
  const int NK = K >> 6;
  for (int ks = 0; ks < NK; ++ks) {
    const int cb = ks & 1;
    if (ks < NK - 1) {
      const size_t ko = (size_t)(ks + 1) * 64;
      gload16(ag + ko, &a_sm[cb ^ 1][w * 8][0]);
      gload16(ag + ko + (size_t)32 * K, &a_sm[cb ^ 1][w * 8 + 32][0]);
      gload16(bg + ko, &b_sm[cb ^ 1][w * 8][0]);
      gload16(bg + ko + (size_t)32 * K, &b_sm[cb ^ 1][w * 8 + 32][0]);
    }
#pragma unroll
    for (int kc = 0; kc < 2; ++kc) {
      const int co = (kc * 64 + g * 16) ^ rx;
      short8 af0 = *(const short8*)((const char*)&a_sm[cb][wm + c16][0] + co);
      short8 af1 = *(const short8*)((const char*)&a_sm[cb][wm + 16 + c16][0] + co);
      short8 bf0 = *(const short8*)((const char*)&b_sm[cb][wn + c16][0] + co);
      short8 bf1 = *(const short8*)((const char*)&b_sm[cb][wn + 16 + c16][0] + co);
      acc[0][0] = mfma16(af0, bf0, acc[0][0]);
      acc[0][1] = mfma16(af0, bf1, acc[0][1]);
      acc[1][0] = mfma16(af1, bf0, acc[1][0]);
      acc[1][1] = mfma16(af1, bf1, acc[1][1]);
    }
    __syncthreads();
  }
#pragma unroll
  for (int fm = 0; fm < 2; ++fm)
#pragma unroll
    for (int fn = 0; fn < 2; ++fn)
#pragma unroll
      for (int r = 0; r < 4; ++r) {
        int row = m0 + wm + fm * 16 + g * 4 + r;
        int col = n0 + wn + fn * 16 + c16;
        float v = acc[fm][fn][r];
        if (HAS_BIAS) v += bias[col];
        v *= scale;
        if (OUT_BF16)
          ((unsigned short*)Cv)[(size_t)row * Nc + col] = f2bf(v);
        else
          ((float*)Cv)[(size_t)row * Nc + col] = v;
      }
}

// ---------------------------------------------------------------- PairNorm stats
__global__ __launch_bounds__(256) void colstat_k(const float* __restrict__ hin,
                                                 float* __restrict__ colsum,
                                                 float* __restrict__ sumsq) {
  const int t = threadIdx.x;
  const int r0 = blockIdx.x * 32;
  float a0 = 0.f, a1 = 0.f, sq = 0.f;
  for (int r = 0; r < 32; ++r) {
    float v0 = hin[(size_t)(r0 + r) * DD + t];
    float v1 = hin[(size_t)(r0 + r) * DD + 256 + t];
    a0 += v0; a1 += v1;
    sq += v0 * v0 + v1 * v1;
  }
  atomicAdd(&colsum[t], a0);
  atomicAdd(&colsum[t + 256], a1);
#pragma unroll
  for (int m = 1; m <= 32; m <<= 1) sq += __shfl_xor(sq, m);
  __shared__ float rr[4];
  int w = t >> 6, lane = t & 63;
  if (lane == 0) rr[w] = sq;
  __syncthreads();
  if (t == 0) atomicAdd(sumsq, rr[0] + rr[1] + rr[2] + rr[3]);
}

__global__ __launch_bounds__(256) void finalize_pn_k(const float* __restrict__ colsum,
                                                     const float* __restrict__ sumsq,
                                                     float* __restrict__ mu,
                                                     float* __restrict__ rnp) {
  const int t = threadIdx.x;
  float m0 = colsum[t] * (1.f / (float)NN);
  float m1 = colsum[t + 256] * (1.f / (float)NN);
  mu[t] = m0;
  mu[t + 256] = m1;
  float sq = m0 * m0 + m1 * m1;
#pragma unroll
  for (int m = 1; m <= 32; m <<= 1) sq += __shfl_xor(sq, m);
  __shared__ float rr[4];
  int w = t >> 6, lane = t & 63;
  if (lane == 0) rr[w] = sq;
  __syncthreads();
  if (t == 0) {
    float musq = rr[0] + rr[1] + rr[2] + rr[3];
    *rnp = rsqrtf(1e-5f + (*sumsq) * (1.f / (float)NN) - musq);
  }
}

// ---------------------------------------------------------------- fused row ops
// PN: h=(hin-mu)*rn; relu(h)+h; LN. Always writes bf16 outb; optionally f32 outf.
template <bool PN, bool WF32>
__global__ __launch_bounds__(256) void rowfuse_k(const float* __restrict__ hin,
                                                 const float* __restrict__ mu,
                                                 const float* __restrict__ rnp,
                                                 const float* __restrict__ gg,
                                                 const float* __restrict__ bb,
                                                 float* __restrict__ outf,
                                                 unsigned short* __restrict__ outb) {
  const int row = blockIdx.x, t = threadIdx.x;
  const size_t base = (size_t)row * DD;
  f32x2 vv = *(const f32x2*)&hin[base + 2 * t];
  float v0 = vv[0], v1 = vv[1];
  if (PN) {
    float rn = *rnp;
    v0 = (v0 - mu[2 * t]) * rn;
    v1 = (v1 - mu[2 * t + 1]) * rn;
    v0 = fmaxf(v0, 0.f) + v0;
    v1 = fmaxf(v1, 0.f) + v1;
  }
  float s1 = v0 + v1, s2 = v0 * v0 + v1 * v1;
#pragma unroll
  for (int m = 1; m <= 32; m <<= 1) {
    s1 += __shfl_xor(s1, m);
    s2 += __shfl_xor(s2, m);
  }
  __shared__ float r1[4], r2[4];
  int w = t >> 6, lane = t & 63;
  if (lane == 0) { r1[w] = s1; r2[w] = s2; }
  __syncthreads();
  s1 = r1[0] + r1[1] + r1[2] + r1[3];
  s2 = r2[0] + r2[1] + r2[2] + r2[3];
  float mean = s1 * (1.f / (float)DD);
  float var = s2 * (1.f / (float)DD) - mean * mean;
  float inv = rsqrtf(var + 1e-5f);
  float y0 = (v0 - mean) * inv * gg[2 * t] + bb[2 * t];
  float y1 = (v1 - mean) * inv * gg[2 * t + 1] + bb[2 * t + 1];
  if (WF32) {
    f32x2 yo = {y0, y1};
    *(f32x2*)&outf[base + 2 * t] = yo;
  }
  *(unsigned*)&outb[base + 2 * t] = (unsigned)f2bf(y0) | ((unsigned)f2bf(y1) << 16);
}

// ---------------------------------------------------------------- [512][4096] -> [4096][512] bf16 transpose
__global__ __launch_bounds__(256) void transpose_pk(const unsigned short* __restrict__ in,
                                                    unsigned short* __restrict__ out) {
  __shared__ __align__(16) unsigned short sm[64][72];
  const int m0 = blockIdx.x * 64, p0 = blockIdx.y * 64;
  const int t = threadIdx.x;
  const int r = t >> 2, q = (t & 3) * 16;
  *(short8*)&sm[r][q] = *(const short8*)&in[(size_t)(p0 + r) * NN + m0 + q];
  *(short8*)&sm[r][q + 8] = *(const short8*)&in[(size_t)(p0 + r) * NN + m0 + q + 8];
  __syncthreads();
  short8 s0, s1;
#pragma unroll
  for (int j = 0; j < 8; ++j) {
    s0[j] = (short)sm[q + j][r];
    s1[j] = (short)sm[q + 8 + j][r];
  }
  *(short8*)&out[(size_t)(m0 + r) * DD + p0 + q] = s0;
  *(short8*)&out[(size_t)(m0 + r) * DD + p0 + q + 8] = s1;
}

// ---------------------------------------------------------------- flash attention, split-K
// R6-verified structure; R7: ones-column MFMA row-sum, __any overflow guard,
// bf16 unnormalized partials.
__global__ __launch_bounds__(256, 4) void attn_k(const unsigned short* __restrict__ Qt,
                                                 const unsigned short* __restrict__ Kt,
                                                 const unsigned short* __restrict__ Vb,
                                                 unsigned short* __restrict__ Op0,
                                                 unsigned short* __restrict__ Op1,
                                                 float* __restrict__ ms) {
  __shared__ __align__(16) unsigned short k_sm[2][64][64];
  __shared__ __align__(16) unsigned short v_sm[2][64][64];
  __shared__ __align__(16) unsigned short p_sm[4][16][64];
  const int tid = threadIdx.x, w = tid >> 6, lane = tid & 63;
  const int g = lane >> 4, c16 = lane & 15;
  const int h = blockIdx.y, z = blockIdx.z;
  const int zbase = z * (NN / 2);
  const int l0 = blockIdx.x * 64 + w * 16;
  unsigned short* __restrict__ Op = z ? Op1 : Op0;

  short8 qf0 = *(const short8*)&Qt[(size_t)(l0 + c16) * DD + h * 64 + g * 8];
  short8 qf1 = *(const short8*)&Qt[(size_t)(l0 + c16) * DD + h * 64 + 32 + g * 8];

  const int srow = lane >> 3, cg = lane & 7;
  const int swz = ((cg * 16) ^ (srow << 4)) >> 1;
  const unsigned short* kgbase = Kt + (size_t)(zbase + w * 16 + srow) * DD + h * 64 + swz;
  const unsigned short* vgbase = Vb + (size_t)(h * 64 + w * 16 + srow) * NN + zbase + swz;

  gload16(kgbase, &k_sm[0][w * 16][0]);
  gload16(kgbase + (size_t)8 * DD, &k_sm[0][w * 16 + 8][0]);
  gload16(vgbase, &v_sm[0][w * 16][0]);
  gload16(vgbase + (size_t)8 * NN, &v_sm[0][w * 16 + 8][0]);
  __syncthreads();

  float M = 0.f;
  f32x4 sacc = {};   // row sums via ones-column MFMA
  f32x4 oacc[4] = {};
  const int sx = (c16 & 7) << 4;
  short8 ones8;
#pragma unroll
  for (int j = 0; j < 8; ++j) ones8[j] = (short)0x3F80;  // bf16 1.0

  for (int t = 0; t < 32; ++t) {
    const int cb = t & 1;
    if (t < 31) {
      const size_t ko = (size_t)(t + 1) * 64 * DD;
      gload16(kgbase + ko, &k_sm[cb ^ 1][w * 16][0]);
      gload16(kgbase + ko + (size_t)8 * DD, &k_sm[cb ^ 1][w * 16 + 8][0]);
      gload16(vgbase + (t + 1) * 64, &v_sm[cb ^ 1][w * 16][0]);
      gload16(vgbase + (t + 1) * 64 + (size_t)8 * NN, &v_sm[cb ^ 1][w * 16 + 8][0]);
    }
    // QK^T
    f32x4 sf[4] = {};
#pragma unroll
    for (int fn = 0; fn < 4; ++fn) {
      const char* kr = (const char*)&k_sm[cb][fn * 16 + c16][0];
      short8 b0 = *(const short8*)(kr + ((g * 16) ^ sx));
      short8 b1 = *(const short8*)(kr + ((64 + g * 16) ^ sx));
      sf[fn] = mfma16(qf0, b0, sf[fn]);
      sf[fn] = mfma16(qf1, b1, sf[fn]);
    }
    // overflow guard (cold): wave-uniform M stays unless scores approach exp range
    float a0 = fmaxf(fmaxf(sf[0][0], sf[0][1]), fmaxf(sf[0][2], sf[0][3]));
    float a1 = fmaxf(fmaxf(sf[1][0], sf[1][1]), fmaxf(sf[1][2], sf[1][3]));
    float a2 = fmaxf(fmaxf(sf[2][0], sf[2][1]), fmaxf(sf[2][2], sf[2][3]));
    float a3 = fmaxf(fmaxf(sf[3][0], sf[3][1]), fmaxf(sf[3][2], sf[3][3]));
    float amax = fmaxf(fmaxf(a0, a1), fmaxf(a2, a3));
    if (__any(amax > M + 25.f)) {
      float wmax = amax;
#pragma unroll
      for (int m = 1; m <= 32; m <<= 1) wmax = fmaxf(wmax, __shfl_xor(wmax, m));
      float alpha = __expf(M - wmax);
#pragma unroll
      for (int r = 0; r < 4; ++r) sacc[r] *= alpha;
#pragma unroll
      for (int fd = 0; fd < 4; ++fd)
#pragma unroll
        for (int r = 0; r < 4; ++r) oacc[fd][r] *= alpha;
      M = wmax;
    }
#pragma unroll
    for (int fn = 0; fn < 4; ++fn)
#pragma unroll
      for (int r = 0; r < 4; ++r) sf[fn][r] = __expf(sf[fn][r] - M);
    // P -> per-wave LDS strip (A-operand layout)
#pragma unroll
    for (int fn = 0; fn < 4; ++fn)
#pragma unroll
      for (int r = 0; r < 4; ++r) p_sm[w][g * 4 + r][fn * 16 + c16] = f2bf(sf[fn][r]);
    // PV + ones-column row-sum (both on the idle MFMA pipe)
#pragma unroll
    for (int kk = 0; kk < 2; ++kk) {
      short8 pa = *(const short8*)&p_sm[w][c16][kk * 32 + g * 8];
      sacc = mfma16(pa, ones8, sacc);
#pragma unroll
      for (int fd = 0; fd < 4; ++fd) {
        const char* vr = (const char*)&v_sm[cb][fd * 16 + c16][0];
        short8 vbf = *(const short8*)(vr + ((kk * 64 + g * 16) ^ sx));
        oacc[fd] = mfma16(pa, vbf, oacc[fd]);
      }
    }
    __syncthreads();
  }
#pragma unroll
  for (int fd = 0; fd < 4; ++fd)
#pragma unroll
    for (int r = 0; r < 4; ++r) {
      int l = l0 + g * 4 + r;
      Op[((size_t)h * NN + l) * DH + fd * 16 + c16] = f2bf(oacc[fd][r]);
    }
  if (c16 == 0) {
#pragma unroll
    for (int r = 0; r < 4; ++r) {
      int hl = h * NN + l0 + g * 4 + r;
      f32x2 pr = {M, sacc[r]};
      *(f32x2*)&ms[((size_t)z * (HH * NN) + hl) * 2] = pr;
    }
  }
}

// merge halves: out = (w0*O0 + w1*O1) / (w0*s0 + w1*s1), bf16 in/out
__global__ __launch_bounds__(256) void attn_merge_k(const unsigned short* __restrict__ Op0,
                                                    const unsigned short* __restrict__ Op1,
                                                    const float* __restrict__ ms,
                                                    unsigned short* __restrict__ Out) {
  const int t = threadIdx.x;
  const int hl = blockIdx.x * 4 + (t >> 6);
  const int d = t & 63;
  float M0 = ms[(size_t)hl * 2], s0 = ms[(size_t)hl * 2 + 1];
  float M1 = ms[((size_t)(HH * NN) + hl) * 2], s1 = ms[((size_t)(HH * NN) + hl) * 2 + 1];
  float M = fmaxf(M0, M1);
  float w0 = __expf(M0 - M), w1 = __expf(M1 - M);
  float inv = 1.f / (w0 * s0 + w1 * s1);
  size_t idx = (size_t)hl * DH + d;
  Out[idx] = f2bf((w0 * bf2f(Op0[idx]) + w1 * bf2f(Op1[idx])) * inv);
}

// ---------------------------------------------------------------- launch
extern "C" void kernel_launch(void* const* d_in, const int* in_sizes, int n_in,
                              void* d_out, int out_size, void* d_ws, size_t ws_size,
                              hipStream_t stream) {
  const float* x = (const float*)d_in[0];
  const int* ei = (const int*)d_in[1];
  const float* Wg = (const float*)d_in[3];
  const float* ln1g = (const float*)d_in[4];
  const float* ln1b = (const float*)d_in[5];
  const float* Wq = (const float*)d_in[6];
  const float* bq = (const float*)d_in[7];
  const float* Wk = (const float*)d_in[8];
  const float* bk = (const float*)d_in[9];
  const float* Wv = (const float*)d_in[10];
  const float* bv = (const float*)d_in[11];
  const float* Wo = (const float*)d_in[12];
  const float* bo = (const float*)d_in[13];
  const float* ln2g = (const float*)d_in[14];
  const float* ln2b = (const float*)d_in[15];
  float* out = (float*)d_out;

  // ---- workspace layout
  char* p = (char*)d_ws;
  float* deg = (float*)p;            // 4096
  float* dinv = deg + 4096;          // 4096
  float* colsum = deg + 8192;        // 512 (+sumsq adjacent)
  float* sumsq = deg + 8704;         // 1
  float* mu = deg + 8768;            // 512
  float* rnp = deg + 9280;           // 1
  float* h1 = deg + 16384;           // [4096][512] f32 (gather out / Wo out)
  unsigned short* xb = (unsigned short*)(h1 + (1u << 21));  // 7 bf16 act buffers, 2M shorts each
  unsigned short* actb = xb + (1u << 21);
  unsigned short* h4b = actb + (1u << 21);
  unsigned short* proj = h4b + (1u << 21);
  unsigned short* Vb = proj + (1u << 21);
  unsigned short* Qt = Vb + (1u << 21);
  unsigned short* Kt = Qt + (1u << 21);
  unsigned short* wb = Kt + (1u << 21);  // 10 x 262144 shorts
  float* msbuf = (float*)(wb + 10u * 262144);  // 131072 f32
  int* rowstart = (int*)(msbuf + 131072);      // 4104
  int* cursor = rowstart + 4104;               // 4096
  int* ecol = cursor + 4096;                   // E
  float* ewt = (float*)(ecol + EE);            // E
  const size_t needed = (size_t)((char*)(ewt + EE) - (char*)d_ws);
  if (ws_size < needed) return;

  unsigned short* Op0b = (unsigned short*)h1;  // dead f32 region during attn
  unsigned short* Op1b = h4b;                  // dead after V-gemm

  const float SCALE = 0.044194173824159216f;  // 1/sqrt(512)
  const size_t WS = (size_t)DD * DD;
  const int W4 = 65536;  // 512*512/4

  hipMemsetAsync(deg, 0, 4096 * sizeof(float), stream);
  deg_k<<<EE / 256, 256, 0, stream>>>(ei, deg);
  dinv_k<<<NN / 256, 256, 0, stream>>>(deg, dinv);
  scan_k<<<1, 256, 0, stream>>>(deg, rowstart, cursor);
  csr_fill_k<<<EE / 256, 256, 0, stream>>>(ei, dinv, cursor, ecol, ewt);

  // one-time converts: x and all weights to bf16 (Wg transposed)
  cvt_k<<<2048, 256, 0, stream>>>(x, xb, 524288);
  for (int i = 0; i < 2; ++i) {
    wtr_k<<<dim3(8, 8), 256, 0, stream>>>(Wg + i * WS, wb + (0 + i) * 262144);
    cvt_k<<<256, 256, 0, stream>>>(Wq + i * WS, wb + (2 + i) * 262144, W4);
    cvt_k<<<256, 256, 0, stream>>>(Wk + i * WS, wb + (4 + i) * 262144, W4);
    cvt_k<<<256, 256, 0, stream>>>(Wv + i * WS, wb + (6 + i) * 262144, W4);
    cvt_k<<<256, 256, 0, stream>>>(Wo + i * WS, wb + (8 + i) * 262144, W4);
  }

  const dim3 gg(8, 64);
  for (int i = 0; i < 2; ++i) {
    // GCN: actb = xb @ WgT^T (bf16)
    gemm_bt_k<false, true><<<gg, 256, 0, stream>>>(
        xb, wb + (0 + i) * 262144, nullptr, 1.f, actb, NN, DD, DD);
    gather_k<<<NN, 256, 0, stream>>>(actb, rowstart, ecol, ewt, h1);
    hipMemsetAsync(colsum, 0, 513 * sizeof(float), stream);
    colstat_k<<<128, 256, 0, stream>>>(h1, colsum, sumsq);
    finalize_pn_k<<<1, 256, 0, stream>>>(colsum, sumsq, mu, rnp);
    rowfuse_k<true, false><<<NN, 256, 0, stream>>>(h1, mu, rnp, ln1g + i * DD, ln1b + i * DD,
                                                   nullptr, h4b);
    // projections
    gemm_bt_k<true, true><<<gg, 256, 0, stream>>>(
        h4b, wb + (2 + i) * 262144, bq + i * DD, SCALE, proj, NN, DD, DD);
    transpose_pk<<<dim3(64, 8), 256, 0, stream>>>(proj, Qt);
    gemm_bt_k<true, true><<<gg, 256, 0, stream>>>(
        h4b, wb + (4 + i) * 262144, bk + i * DD, SCALE, proj, NN, DD, DD);
    transpose_pk<<<dim3(64, 8), 256, 0, stream>>>(proj, Kt);
    gemm_bt_k<true, true><<<gg, 256, 0, stream>>>(
        h4b, wb + (6 + i) * 262144, bv + i * DD, 1.f, Vb, NN, DD, DD);
    // attention (split-K=2)
    attn_k<<<dim3(64, 8, 2), 256, 0, stream>>>(Qt, Kt, Vb, Op0b, Op1b, msbuf);
    attn_merge_k<<<HH * NN / 4, 256, 0, stream>>>(Op0b, Op1b, msbuf, actb);
    // output projection + LN2
    gemm_bt_k<true, false><<<gg, 256, 0, stream>>>(
        actb, wb + (8 + i) * 262144, bo + i * DD, 1.f, h1, NN, DD, DD);
    rowfuse_k<false, true><<<NN, 256, 0, stream>>>(h1, nullptr, nullptr, ln2g + i * DD,
                                                   ln2b + i * DD, out, xb);
  }
}

// Round 10
// 432.256 us; speedup vs baseline: 10.3182x; 1.0589x over previous
//
#include <hip/hip_runtime.h>

// GNN_44942537785535 — MI355X bf16-MFMA implementation.
// N=4096, D=512, H=8, DH=64, E=131072, L=2.
// R1: CSR gather replaces atomic scatter (4460 -> 941 us).
// R6: attn m97-template rebuild + split-K=2 (941 -> 627 us).
// R9: bf16 GEMM overhaul + bf16 gather + attn VALU cuts (627 -> 458 us).
// R10: (a) p_sm XOR-swizzle (kills the measured 7.3M 16-way bank conflict on
//      the PV read); (b) f2bf via native __bf16 cast (1 op vs 5);
//      (c) batched converts/transposes (-10 dispatches).
// Workspace: ~44.7 MB (guarded).

#define NN 4096
#define DD 512
#define HH 8
#define DH 64
#define EE 131072

typedef float f32x2 __attribute__((ext_vector_type(2)));
typedef float f32x4 __attribute__((ext_vector_type(4)));
typedef short short8 __attribute__((ext_vector_type(8)));
typedef unsigned short u16x4 __attribute__((ext_vector_type(4)));
typedef __bf16 bf16x8 __attribute__((ext_vector_type(8)));

static __device__ __forceinline__ unsigned short f2bf(float f) {
  return __builtin_bit_cast(unsigned short, (__bf16)f);  // RNE, single v_cvt
}
static __device__ __forceinline__ float bf2f(unsigned short s) {
  return __uint_as_float(((unsigned)s) << 16);
}

static __device__ __forceinline__ f32x4 mfma16(short8 a, short8 b, f32x4 c) {
  return __builtin_amdgcn_mfma_f32_16x16x32_bf16(
      __builtin_bit_cast(bf16x8, a), __builtin_bit_cast(bf16x8, b), c, 0, 0, 0);
}

static __device__ __forceinline__ void gload16(const unsigned short* g, unsigned short* l) {
  __builtin_amdgcn_global_load_lds((const __attribute__((address_space(1))) unsigned int*)g,
                                   (__attribute__((address_space(3))) unsigned int*)l, 16, 0, 0);
}

// ---------------------------------------------------------------- degree/dinv
__global__ __launch_bounds__(256) void deg_k(const int* __restrict__ ei, float* __restrict__ deg) {
  int t = blockIdx.x * 256 + threadIdx.x;
  atomicAdd(&deg[ei[EE + t]], 1.0f);
}

__global__ __launch_bounds__(256) void dinv_k(const float* __restrict__ deg, float* __restrict__ dinv) {
  int t = blockIdx.x * 256 + threadIdx.x;
  float dg = deg[t];
  dinv[t] = dg > 0.f ? rsqrtf(fmaxf(dg, 1e-12f)) : 0.f;
}

// ---------------------------------------------------------------- CSR build
__global__ __launch_bounds__(256) void scan_k(const float* __restrict__ deg,
                                              int* __restrict__ rowstart,
                                              int* __restrict__ cursor) {
  __shared__ int part[256];
  const int t = threadIdx.x;
  int loc[16];
  int s = 0;
#pragma unroll
  for (int j = 0; j < 16; ++j) {
    loc[j] = s;
    s += (int)deg[t * 16 + j];
  }
  part[t] = s;
  __syncthreads();
  for (int off = 1; off < 256; off <<= 1) {
    int v = (t >= off) ? part[t - off] : 0;
    __syncthreads();
    part[t] += v;
    __syncthreads();
  }
  int base = (t > 0) ? part[t - 1] : 0;
#pragma unroll
  for (int j = 0; j < 16; ++j) {
    int rs = base + loc[j];
    rowstart[t * 16 + j] = rs;
    cursor[t * 16 + j] = rs;
  }
  if (t == 255) rowstart[4096] = part[255];
}

__global__ __launch_bounds__(256) void csr_fill_k(const int* __restrict__ ei,
                                                  const float* __restrict__ dinv,
                                                  int* __restrict__ cursor,
                                                  int* __restrict__ ecol,
                                                  float* __restrict__ ewt) {
  int e = blockIdx.x * 256 + threadIdx.x;
  int s = ei[e], d = ei[EE + e];
  int pos = atomicAdd(&cursor[d], 1);
  ecol[pos] = s;
  ewt[pos] = dinv[s] * dinv[d];
}

// ---------------------------------------------------------------- converts
__global__ __launch_bounds__(256) void cvt_k(const float* __restrict__ s,
                                             unsigned short* __restrict__ d, int n4) {
  int i = blockIdx.x * 256 + threadIdx.x;
  if (i < n4) {
    f32x4 v = *(const f32x4*)&s[i * 4];
    u16x4 o;
#pragma unroll
    for (int j = 0; j < 4; ++j) o[j] = f2bf(v[j]);
    *(u16x4*)&d[i * 4] = o;
  }
}

struct P8 { const float* p[8]; };
// 8 weight matrices [512x512] f32 -> bf16, one kernel (blockIdx.y selects)
__global__ __launch_bounds__(256) void cvt8_k(P8 s, unsigned short* __restrict__ d) {
  const int which = blockIdx.y;
  const float* src = s.p[which];
  unsigned short* dst = d + (size_t)which * 262144;
  int i = blockIdx.x * 256 + threadIdx.x;
  f32x4 v = *(const f32x4*)&src[i * 4];
  u16x4 o;
#pragma unroll
  for (int j = 0; j < 4; ++j) o[j] = f2bf(v[j]);
  *(u16x4*)&dst[i * 4] = o;
}

// Wg[z] [512 k][512 j] f32 -> WgT [512 j][512 k] bf16 (both layers in one grid)
__global__ __launch_bounds__(256) void wtr2_k(const float* __restrict__ in,
                                              unsigned short* __restrict__ out) {
  __shared__ unsigned short sm[64][72];
  const int z = blockIdx.z;
  const float* inz = in + (size_t)z * DD * DD;
  unsigned short* outz = out + (size_t)z * 262144;
  const int k0 = blockIdx.y * 64, j0 = blockIdx.x * 64;
  const int t = threadIdx.x;
  const int r = t >> 2, q = (t & 3) * 16;
  const float* src = inz + (size_t)(k0 + r) * 512 + j0 + q;
#pragma unroll
  for (int jj = 0; jj < 16; ++jj) sm[r][q + jj] = f2bf(src[jj]);
  __syncthreads();
  short8 s0, s1;
#pragma unroll
  for (int j = 0; j < 8; ++j) {
    s0[j] = (short)sm[q + j][r];
    s1[j] = (short)sm[q + 8 + j][r];
  }
  *(short8*)&outz[(size_t)(j0 + r) * 512 + k0 + q] = s0;
  *(short8*)&outz[(size_t)(j0 + r) * 512 + k0 + q + 8] = s1;
}

// ---------------------------------------------------------------- GCN aggregation (bf16 in, f32 out)
__global__ __launch_bounds__(256) void gather_k(const unsigned short* __restrict__ hb,
                                                const int* __restrict__ rowstart,
                                                const int* __restrict__ ecol,
                                                const float* __restrict__ ewt,
                                                float* __restrict__ h1) {
  __shared__ int s_col[256];
  __shared__ float s_w[256];
  const int node = blockIdx.x, t = threadIdx.x;
  const int beg = rowstart[node], end = rowstart[node + 1];
  float a0 = 0.f, a1 = 0.f;
  for (int base = beg; base < end; base += 256) {
    int n = min(256, end - base);
    __syncthreads();
    if (t < n) {
      s_col[t] = ecol[base + t];
      s_w[t] = ewt[base + t];
    }
    __syncthreads();
    for (int j = 0; j < n; ++j) {
      int s = s_col[j];
      float en = s_w[j];
      unsigned v = *(const unsigned*)&hb[(size_t)s * DD + 2 * t];
      a0 += en * __uint_as_float(v << 16);
      a1 += en * __uint_as_float(v & 0xFFFF0000u);
    }
  }
  f32x2 acc = {a0, a1};
  *(f32x2*)&h1[(size_t)node * DD + 2 * t] = acc;
}

// ---------------------------------------------------------------- bf16 GEMM (m97-style)
// C[M,Nc] = A[M,K] @ B[Nc,K]^T (both bf16), epilogue (acc+bias)*scale.
template <bool HAS_BIAS, bool OUT_BF16>
__global__ __launch_bounds__(256) void gemm_bt_k(const unsigned short* __restrict__ A,
                                                 const unsigned short* __restrict__ B,
                                                 const float* __restrict__ bias, float scale,
                                                 void* __restrict__ Cv, int M, int Nc, int K) {
  __shared__ __align__(16) unsigned short a_sm[2][64][64];
  __shared__ __align__(16) unsigned short b_sm[2][64][64];
  const int tid = threadIdx.x, w = tid >> 6, lane = tid & 63;
  const int g = lane >> 4, c16 = lane & 15;
  const int n0 = blockIdx.x * 64, m0 = blockIdx.y * 64;
  const int wm = (w >> 1) * 32, wn = (w & 1) * 32;
  const int srow = lane >> 3, cg = lane & 7;
  const int swz = ((cg * 16) ^ (srow << 4)) >> 1;
  const unsigned short* ag = A + (size_t)(m0 + w * 8 + srow) * K + swz;
  const unsigned short* bg = B + (size_t)(n0 + w * 8 + srow) * K + swz;
  f32x4 acc[2][2] = {};

  gload16(ag, &a_sm[0][w * 8][0]);
  gload16(ag + (size_t)32 * K, &a_sm[0][w * 8 + 32][0]);
  gload16(bg, &b_sm[0][w * 8][0]);
  gload16(bg + (size_t)32 * K, &b_sm[0][w * 8 + 32][0]);
  __syncthreads();

  const int rx = (c16 & 7) << 4;
  const int NK = K >> 6;
  for (int ks = 0; ks < NK; ++ks) {
    const int cb = ks & 1;
    if (ks < NK - 1) {
      const size_t ko = (size_t)(ks + 1) * 64;
      gload16(ag + ko, &a_sm[cb ^ 1][w * 8][0]);
      gload16(ag + ko + (size_t)32 * K, &a_sm[cb ^ 1][w * 8 + 32][0]);
      gload16(bg + ko, &b_sm[cb ^ 1][w * 8][0]);
      gload16(bg + ko + (size_t)32 * K, &b_sm[cb ^ 1][w * 8 + 32][0]);
    }
#pragma unroll
    for (int kc = 0; kc < 2; ++kc) {
      const int co = (kc * 64 + g * 16) ^ rx;
      short8 af0 = *(const short8*)((const char*)&a_sm[cb][wm + c16][0] + co);
      short8 af1 = *(const short8*)((const char*)&a_sm[cb][wm + 16 + c16][0] + co);
      short8 bf0 = *(const short8*)((const char*)&b_sm[cb][wn + c16][0] + co);
      short8 bf1 = *(const short8*)((const char*)&b_sm[cb][wn + 16 + c16][0] + co);
      acc[0][0] = mfma16(af0, bf0, acc[0][0]);
      acc[0][1] = mfma16(af0, bf1, acc[0][1]);
      acc[1][0] = mfma16(af1, bf0, acc[1][0]);
      acc[1][1] = mfma16(af1, bf1, acc[1][1]);
    }
    __syncthreads();
  }
#pragma unroll
  for (int fm = 0; fm < 2; ++fm)
#pragma unroll
    for (int fn = 0; fn < 2; ++fn)
#pragma unroll
      for (int r = 0; r < 4; ++r) {
        int row = m0 + wm + fm * 16 + g * 4 + r;
        int col = n0 + wn + fn * 16 + c16;
        float v = acc[fm][fn][r];
        if (HAS_BIAS) v += bias[col];
        v *= scale;
        if (OUT_BF16)
          ((unsigned short*)Cv)[(size_t)row * Nc + col] = f2bf(v);
        else
          ((float*)Cv)[(size_t)row * Nc + col] = v;
      }
}

// ---------------------------------------------------------------- PairNorm stats
__global__ __launch_bounds__(256) void colstat_k(const float* __restrict__ hin,
                                                 float* __restrict__ colsum,
                                                 float* __restrict__ sumsq) {
  const int t = threadIdx.x;
  const int r0 = blockIdx.x * 32;
  float a0 = 0.f, a1 = 0.f, sq = 0.f;
  for (int r = 0; r < 32; ++r) {
    float v0 = hin[(size_t)(r0 + r) * DD + t];
    float v1 = hin[(size_t)(r0 + r) * DD + 256 + t];
    a0 += v0; a1 += v1;
    sq += v0 * v0 + v1 * v1;
  }
  atomicAdd(&colsum[t], a0);
  atomicAdd(&colsum[t + 256], a1);
#pragma unroll
  for (int m = 1; m <= 32; m <<= 1) sq += __shfl_xor(sq, m);
  __shared__ float rr[4];
  int w = t >> 6, lane = t & 63;
  if (lane == 0) rr[w] = sq;
  __syncthreads();
  if (t == 0) atomicAdd(sumsq, rr[0] + rr[1] + rr[2] + rr[3]);
}

__global__ __launch_bounds__(256) void finalize_pn_k(const float* __restrict__ colsum,
                                                     const float* __restrict__ sumsq,
                                                     float* __restrict__ mu,
                                                     float* __restrict__ rnp) {
  const int t = threadIdx.x;
  float m0 = colsum[t] * (1.f / (float)NN);
  float m1 = colsum[t + 256] * (1.f / (float)NN);
  mu[t] = m0;
  mu[t + 256] = m1;
  float sq = m0 * m0 + m1 * m1;
#pragma unroll
  for (int m = 1; m <= 32; m <<= 1) sq += __shfl_xor(sq, m);
  __shared__ float rr[4];
  int w = t >> 6, lane = t & 63;
  if (lane == 0) rr[w] = sq;
  __syncthreads();
  if (t == 0) {
    float musq = rr[0] + rr[1] + rr[2] + rr[3];
    *rnp = rsqrtf(1e-5f + (*sumsq) * (1.f / (float)NN) - musq);
  }
}

// ---------------------------------------------------------------- fused row ops
template <bool PN, bool WF32>
__global__ __launch_bounds__(256) void rowfuse_k(const float* __restrict__ hin,
                                                 const float* __restrict__ mu,
                                                 const float* __restrict__ rnp,
                                                 const float* __restrict__ gg,
                                                 const float* __restrict__ bb,
                                                 float* __restrict__ outf,
                                                 unsigned short* __restrict__ outb) {
  const int row = blockIdx.x, t = threadIdx.x;
  const size_t base = (size_t)row * DD;
  f32x2 vv = *(const f32x2*)&hin[base + 2 * t];
  float v0 = vv[0], v1 = vv[1];
  if (PN) {
    float rn = *rnp;
    v0 = (v0 - mu[2 * t]) * rn;
    v1 = (v1 - mu[2 * t + 1]) * rn;
    v0 = fmaxf(v0, 0.f) + v0;
    v1 = fmaxf(v1, 0.f) + v1;
  }
  float s1 = v0 + v1, s2 = v0 * v0 + v1 * v1;
#pragma unroll
  for (int m = 1; m <= 32; m <<= 1) {
    s1 += __shfl_xor(s1, m);
    s2 += __shfl_xor(s2, m);
  }
  __shared__ float r1[4], r2[4];
  int w = t >> 6, lane = t & 63;
  if (lane == 0) { r1[w] = s1; r2[w] = s2; }
  __syncthreads();
  s1 = r1[0] + r1[1] + r1[2] + r1[3];
  s2 = r2[0] + r2[1] + r2[2] + r2[3];
  float mean = s1 * (1.f / (float)DD);
  float var = s2 * (1.f / (float)DD) - mean * mean;
  float inv = rsqrtf(var + 1e-5f);
  float y0 = (v0 - mean) * inv * gg[2 * t] + bb[2 * t];
  float y1 = (v1 - mean) * inv * gg[2 * t + 1] + bb[2 * t + 1];
  if (WF32) {
    f32x2 yo = {y0, y1};
    *(f32x2*)&outf[base + 2 * t] = yo;
  }
  *(unsigned*)&outb[base + 2 * t] = (unsigned)f2bf(y0) | ((unsigned)f2bf(y1) << 16);
}

// ---------------------------------------------------------------- dual [512][4096] -> [4096][512] bf16 transpose
__global__ __launch_bounds__(256) void transpose2_pk(const unsigned short* __restrict__ in0,
                                                     const unsigned short* __restrict__ in1,
                                                     unsigned short* __restrict__ out0,
                                                     unsigned short* __restrict__ out1) {
  __shared__ __align__(16) unsigned short sm[64][72];
  const unsigned short* in = blockIdx.z ? in1 : in0;
  unsigned short* out = blockIdx.z ? out1 : out0;
  const int m0 = blockIdx.x * 64, p0 = blockIdx.y * 64;
  const int t = threadIdx.x;
  const int r = t >> 2, q = (t & 3) * 16;
  *(short8*)&sm[r][q] = *(const short8*)&in[(size_t)(p0 + r) * NN + m0 + q];
  *(short8*)&sm[r][q + 8] = *(const short8*)&in[(size_t)(p0 + r) * NN + m0 + q + 8];
  __syncthreads();
  short8 s0, s1;
#pragma unroll
  for (int j = 0; j < 8; ++j) {
    s0[j] = (short)sm[q + j][r];
    s1[j] = (short)sm[q + 8 + j][r];
  }
  *(short8*)&out[(size_t)(m0 + r) * DD + p0 + q] = s0;
  *(short8*)&out[(size_t)(m0 + r) * DD + p0 + q + 8] = s1;
}

// ---------------------------------------------------------------- flash attention, split-K
// R9 structure + p_sm XOR-swizzle (write/read same (row&7)<<4 byte-XOR).
__global__ __launch_bounds__(256, 4) void attn_k(const unsigned short* __restrict__ Qt,
                                                 const unsigned short* __restrict__ Kt,
                                                 const unsigned short* __restrict__ Vb,
                                                 unsigned short* __restrict__ Op0,
                                                 unsigned short* __restrict__ Op1,
                                                 float* __restrict__ ms) {
  __shared__ __align__(16) unsigned short k_sm[2][64][64];
  __shared__ __align__(16) unsigned short v_sm[2][64][64];
  __shared__ __align__(16) unsigned short p_sm[4][16][64];
  const int tid = threadIdx.x, w = tid >> 6, lane = tid & 63;
  const int g = lane >> 4, c16 = lane & 15;
  const int h = blockIdx.y, z = blockIdx.z;
  const int zbase = z * (NN / 2);
  const int l0 = blockIdx.x * 64 + w * 16;
  unsigned short* __restrict__ Op = z ? Op1 : Op0;

  short8 qf0 = *(const short8*)&Qt[(size_t)(l0 + c16) * DD + h * 64 + g * 8];
  short8 qf1 = *(const short8*)&Qt[(size_t)(l0 + c16) * DD + h * 64 + 32 + g * 8];

  const int srow = lane >> 3, cg = lane & 7;
  const int swz = ((cg * 16) ^ (srow << 4)) >> 1;
  const unsigned short* kgbase = Kt + (size_t)(zbase + w * 16 + srow) * DD + h * 64 + swz;
  const unsigned short* vgbase = Vb + (size_t)(h * 64 + w * 16 + srow) * NN + zbase + swz;

  gload16(kgbase, &k_sm[0][w * 16][0]);
  gload16(kgbase + (size_t)8 * DD, &k_sm[0][w * 16 + 8][0]);
  gload16(vgbase, &v_sm[0][w * 16][0]);
  gload16(vgbase + (size_t)8 * NN, &v_sm[0][w * 16 + 8][0]);
  __syncthreads();

  float M = 0.f;
  f32x4 sacc = {};   // row sums via ones-column MFMA
  f32x4 oacc[4] = {};
  const int sx = (c16 & 7) << 4;
  short8 ones8;
#pragma unroll
  for (int j = 0; j < 8; ++j) ones8[j] = (short)0x3F80;  // bf16 1.0

  for (int t = 0; t < 32; ++t) {
    const int cb = t & 1;
    if (t < 31) {
      const size_t ko = (size_t)(t + 1) * 64 * DD;
      gload16(kgbase + ko, &k_sm[cb ^ 1][w * 16][0]);
      gload16(kgbase + ko + (size_t)8 * DD, &k_sm[cb ^ 1][w * 16 + 8][0]);
      gload16(vgbase + (t + 1) * 64, &v_sm[cb ^ 1][w * 16][0]);
      gload16(vgbase + (t + 1) * 64 + (size_t)8 * NN, &v_sm[cb ^ 1][w * 16 + 8][0]);
    }
    // QK^T
    f32x4 sf[4] = {};
#pragma unroll
    for (int fn = 0; fn < 4; ++fn) {
      const char* kr = (const char*)&k_sm[cb][fn * 16 + c16][0];
      short8 b0 = *(const short8*)(kr + ((g * 16) ^ sx));
      short8 b1 = *(const short8*)(kr + ((64 + g * 16) ^ sx));
      sf[fn] = mfma16(qf0, b0, sf[fn]);
      sf[fn] = mfma16(qf1, b1, sf[fn]);
    }
    // overflow guard (cold)
    float a0 = fmaxf(fmaxf(sf[0][0], sf[0][1]), fmaxf(sf[0][2], sf[0][3]));
    float a1 = fmaxf(fmaxf(sf[1][0], sf[1][1]), fmaxf(sf[1][2], sf[1][3]));
    float a2 = fmaxf(fmaxf(sf[2][0], sf[2][1]), fmaxf(sf[2][2], sf[2][3]));
    float a3 = fmaxf(fmaxf(sf[3][0], sf[3][1]), fmaxf(sf[3][2], sf[3][3]));
    float amax = fmaxf(fmaxf(a0, a1), fmaxf(a2, a3));
    if (__any(amax > M + 25.f)) {
      float wmax = amax;
#pragma unroll
      for (int m = 1; m <= 32; m <<= 1) wmax = fmaxf(wmax, __shfl_xor(wmax, m));
      float alpha = __expf(M - wmax);
#pragma unroll
      for (int r = 0; r < 4; ++r) sacc[r] *= alpha;
#pragma unroll
      for (int fd = 0; fd < 4; ++fd)
#pragma unroll
        for (int r = 0; r < 4; ++r) oacc[fd][r] *= alpha;
      M = wmax;
    }
#pragma unroll
    for (int fn = 0; fn < 4; ++fn)
#pragma unroll
      for (int r = 0; r < 4; ++r) sf[fn][r] = __expf(sf[fn][r] - M);
    // P -> per-wave LDS strip (A-operand layout), XOR-swizzled by row
#pragma unroll
    for (int fn = 0; fn < 4; ++fn)
#pragma unroll
      for (int r = 0; r < 4; ++r) {
        const int prow = g * 4 + r;
        const int pb = ((fn * 16 + c16) * 2) ^ ((prow & 7) << 4);
        *(unsigned short*)((char*)&p_sm[w][prow][0] + pb) = f2bf(sf[fn][r]);
      }
    // PV + ones-column row-sum (both on MFMA pipe); read applies same XOR
#pragma unroll
    for (int kk = 0; kk < 2; ++kk) {
      const int rb = (kk * 64 + g * 16) ^ ((c16 & 7) << 4);
      short8 pa = *(const short8*)((const char*)&p_sm[w][c16][0] + rb);
      sacc = mfma16(pa, ones8, sacc);
#pragma unroll
      for (int fd = 0; fd < 4; ++fd) {
        const char* vr = (const char*)&v_sm[cb][fd * 16 + c16][0];
        short8 vbf = *(const short8*)(vr + ((kk * 64 + g * 16) ^ sx));
        oacc[fd] = mfma16(pa, vbf, oacc[fd]);
      }
    }
    __syncthreads();
  }
#pragma unroll
  for (int fd = 0; fd < 4; ++fd)
#pragma unroll
    for (int r = 0; r < 4; ++r) {
      int l = l0 + g * 4 + r;
      Op[((size_t)h * NN + l) * DH + fd * 16 + c16] = f2bf(oacc[fd][r]);
    }
  if (c16 == 0) {
#pragma unroll
    for (int r = 0; r < 4; ++r) {
      int hl = h * NN + l0 + g * 4 + r;
      f32x2 pr = {M, sacc[r]};
      *(f32x2*)&ms[((size_t)z * (HH * NN) + hl) * 2] = pr;
    }
  }
}

// merge halves: out = (w0*O0 + w1*O1) / (w0*s0 + w1*s1), bf16 in/out
__global__ __launch_bounds__(256) void attn_merge_k(const unsigned short* __restrict__ Op0,
                                                    const unsigned short* __restrict__ Op1,
                                                    const float* __restrict__ ms,
                                                    unsigned short* __restrict__ Out) {
  const int t = threadIdx.x;
  const int hl = blockIdx.x * 4 + (t >> 6);
  const int d = t & 63;
  float M0 = ms[(size_t)hl * 2], s0 = ms[(size_t)hl * 2 + 1];
  float M1 = ms[((size_t)(HH * NN) + hl) * 2], s1 = ms[((size_t)(HH * NN) + hl) * 2 + 1];
  float M = fmaxf(M0, M1);
  float w0 = __expf(M0 - M), w1 = __expf(M1 - M);
  float inv = 1.f / (w0 * s0 + w1 * s1);
  size_t idx = (size_t)hl * DH + d;
  Out[idx] = f2bf((w0 * bf2f(Op0[idx]) + w1 * bf2f(Op1[idx])) * inv);
}

// ---------------------------------------------------------------- launch
extern "C" void kernel_launch(void* const* d_in, const int* in_sizes, int n_in,
                              void* d_out, int out_size, void* d_ws, size_t ws_size,
                              hipStream_t stream) {
  const float* x = (const float*)d_in[0];
  const int* ei = (const int*)d_in[1];
  const float* Wg = (const float*)d_in[3];
  const float* ln1g = (const float*)d_in[4];
  const float* ln1b = (const float*)d_in[5];
  const float* Wq = (const float*)d_in[6];
  const float* bq = (const float*)d_in[7];
  const float* Wk = (const float*)d_in[8];
  const float* bk = (const float*)d_in[9];
  const float* Wv = (const float*)d_in[10];
  const float* bv = (const float*)d_in[11];
  const float* Wo = (const float*)d_in[12];
  const float* bo = (const float*)d_in[13];
  const float* ln2g = (const float*)d_in[14];
  const float* ln2b = (const float*)d_in[15];
  float* out = (float*)d_out;

  // ---- workspace layout
  char* p = (char*)d_ws;
  float* deg = (float*)p;            // 4096
  float* dinv = deg + 4096;          // 4096
  float* colsum = deg + 8192;        // 512 (+sumsq adjacent)
  float* sumsq = deg + 8704;         // 1
  float* mu = deg + 8768;            // 512
  float* rnp = deg + 9280;           // 1
  float* h1 = deg + 16384;           // [4096][512] f32 (gather out / Wo out)
  unsigned short* xb = (unsigned short*)(h1 + (1u << 21));  // 7 bf16 act buffers, 2M shorts each
  unsigned short* actb = xb + (1u << 21);
  unsigned short* h4b = actb + (1u << 21);
  unsigned short* proj = h4b + (1u << 21);
  unsigned short* Vb = proj + (1u << 21);
  unsigned short* Qt = Vb + (1u << 21);
  unsigned short* Kt = Qt + (1u << 21);
  unsigned short* wb = Kt + (1u << 21);  // 10 x 262144 shorts
  float* msbuf = (float*)(wb + 10u * 262144);  // 131072 f32
  int* rowstart = (int*)(msbuf + 131072);      // 4104
  int* cursor = rowstart + 4104;               // 4096
  int* ecol = cursor + 4096;                   // E
  float* ewt = (float*)(ecol + EE);            // E
  const size_t needed = (size_t)((char*)(ewt + EE) - (char*)d_ws);
  if (ws_size < needed) return;

  unsigned short* Op0b = (unsigned short*)h1;  // dead f32 region during attn
  unsigned short* Op1b = h4b;                  // dead after V-gemm

  const float SCALE = 0.044194173824159216f;  // 1/sqrt(512)
  const size_t WS = (size_t)DD * DD;

  hipMemsetAsync(deg, 0, 4096 * sizeof(float), stream);
  deg_k<<<EE / 256, 256, 0, stream>>>(ei, deg);
  dinv_k<<<NN / 256, 256, 0, stream>>>(deg, dinv);
  scan_k<<<1, 256, 0, stream>>>(deg, rowstart, cursor);
  csr_fill_k<<<EE / 256, 256, 0, stream>>>(ei, dinv, cursor, ecol, ewt);

  // one-time converts: x, Wg (transposed, both layers), 8 projection weights
  cvt_k<<<2048, 256, 0, stream>>>(x, xb, 524288);
  wtr2_k<<<dim3(8, 8, 2), 256, 0, stream>>>(Wg, wb);
  P8 s8;
  s8.p[0] = Wq; s8.p[1] = Wq + WS;
  s8.p[2] = Wk; s8.p[3] = Wk + WS;
  s8.p[4] = Wv; s8.p[5] = Wv + WS;
  s8.p[6] = Wo; s8.p[7] = Wo + WS;
  cvt8_k<<<dim3(256, 8), 256, 0, stream>>>(s8, wb + 2u * 262144);

  const dim3 gg(8, 64);
  for (int i = 0; i < 2; ++i) {
    // GCN: actb = xb @ WgT^T (bf16)
    gemm_bt_k<false, true><<<gg, 256, 0, stream>>>(
        xb, wb + (0 + i) * 262144, nullptr, 1.f, actb, NN, DD, DD);
    gather_k<<<NN, 256, 0, stream>>>(actb, rowstart, ecol, ewt, h1);
    hipMemsetAsync(colsum, 0, 513 * sizeof(float), stream);
    colstat_k<<<128, 256, 0, stream>>>(h1, colsum, sumsq);
    finalize_pn_k<<<1, 256, 0, stream>>>(colsum, sumsq, mu, rnp);
    rowfuse_k<true, false><<<NN, 256, 0, stream>>>(h1, mu, rnp, ln1g + i * DD, ln1b + i * DD,
                                                   nullptr, h4b);
    // projections: Q -> proj, K -> actb (free until merge), V -> Vb
    gemm_bt_k<true, true><<<gg, 256, 0, stream>>>(
        h4b, wb + (2 + i) * 262144, bq + i * DD, SCALE, proj, NN, DD, DD);
    gemm_bt_k<true, true><<<gg, 256, 0, stream>>>(
        h4b, wb + (4 + i) * 262144, bk + i * DD, SCALE, actb, NN, DD, DD);
    gemm_bt_k<true, true><<<gg, 256, 0, stream>>>(
        h4b, wb + (6 + i) * 262144, bv + i * DD, 1.f, Vb, NN, DD, DD);
    transpose2_pk<<<dim3(64, 8, 2), 256, 0, stream>>>(proj, actb, Qt, Kt);
    // attention (split-K=2)
    attn_k<<<dim3(64, 8, 2), 256, 0, stream>>>(Qt, Kt, Vb, Op0b, Op1b, msbuf);
    attn_merge_k<<<HH * NN / 4, 256, 0, stream>>>(Op0b, Op1b, msbuf, actb);
    // output projection + LN2
    gemm_bt_k<true, false><<<gg, 256, 0, stream>>>(
        actb, wb + (8 + i) * 262144, bo + i * DD, 1.f, h1, NN, DD, DD);
    rowfuse_k<false, true><<<NN, 256, 0, stream>>>(h1, nullptr, nullptr, ln2g + i * DD,
                                                   ln2b + i * DD, out, xb);
  }
}

// Round 11
// 430.673 us; speedup vs baseline: 10.3561x; 1.0037x over previous
//
#include <hip/hip_runtime.h>

// GNN_44942537785535 — MI355X bf16-MFMA implementation.
// N=4096, D=512, H=8, DH=64, E=131072, L=2.
// R1: CSR gather replaces atomic scatter (4460 -> 941 us).
// R6: attn m97-template rebuild + split-K=2 (941 -> 627 us).
// R9: bf16 GEMM overhaul + bf16 gather + attn VALU cuts (627 -> 458 us).
// R10: p_sm swizzle (7.3M bank conflicts -> 0) + native f2bf (458 -> 432 us).
// R11: (a) log2-domain softmax (exp2f = native v_exp, no mul; log2e folded
//      into Q scale); (b) XCD-aware attn grid swizzle (per-XCD L2 working set
//      8MB -> 1MB); (c) QKV fused GEMM (3 -> 1 dispatch); (d) gather unroll x4
//      + colsum zero folded in (-2 memsets).
// Workspace: ~44.7 MB (guarded).

#define NN 4096
#define DD 512
#define HH 8
#define DH 64
#define EE 131072

typedef float f32x2 __attribute__((ext_vector_type(2)));
typedef float f32x4 __attribute__((ext_vector_type(4)));
typedef short short8 __attribute__((ext_vector_type(8)));
typedef unsigned short u16x4 __attribute__((ext_vector_type(4)));
typedef __bf16 bf16x8 __attribute__((ext_vector_type(8)));

#define SCALE_K 0.044194173824159216f               // 1/sqrt(512)
#define SCALE_Q 0.06375872343889103f                // SCALE_K * log2(e)

static __device__ __forceinline__ unsigned short f2bf(float f) {
  return __builtin_bit_cast(unsigned short, (__bf16)f);  // RNE, single v_cvt
}
static __device__ __forceinline__ float bf2f(unsigned short s) {
  return __uint_as_float(((unsigned)s) << 16);
}

static __device__ __forceinline__ f32x4 mfma16(short8 a, short8 b, f32x4 c) {
  return __builtin_amdgcn_mfma_f32_16x16x32_bf16(
      __builtin_bit_cast(bf16x8, a), __builtin_bit_cast(bf16x8, b), c, 0, 0, 0);
}

static __device__ __forceinline__ void gload16(const unsigned short* g, unsigned short* l) {
  __builtin_amdgcn_global_load_lds((const __attribute__((address_space(1))) unsigned int*)g,
                                   (__attribute__((address_space(3))) unsigned int*)l, 16, 0, 0);
}

// ---------------------------------------------------------------- degree/dinv
__global__ __launch_bounds__(256) void deg_k(const int* __restrict__ ei, float* __restrict__ deg) {
  int t = blockIdx.x * 256 + threadIdx.x;
  atomicAdd(&deg[ei[EE + t]], 1.0f);
}

__global__ __launch_bounds__(256) void dinv_k(const float* __restrict__ deg, float* __restrict__ dinv) {
  int t = blockIdx.x * 256 + threadIdx.x;
  float dg = deg[t];
  dinv[t] = dg > 0.f ? rsqrtf(fmaxf(dg, 1e-12f)) : 0.f;
}

// ---------------------------------------------------------------- CSR build
__global__ __launch_bounds__(256) void scan_k(const float* __restrict__ deg,
                                              int* __restrict__ rowstart,
                                              int* __restrict__ cursor) {
  __shared__ int part[256];
  const int t = threadIdx.x;
  int loc[16];
  int s = 0;
#pragma unroll
  for (int j = 0; j < 16; ++j) {
    loc[j] = s;
    s += (int)deg[t * 16 + j];
  }
  part[t] = s;
  __syncthreads();
  for (int off = 1; off < 256; off <<= 1) {
    int v = (t >= off) ? part[t - off] : 0;
    __syncthreads();
    part[t] += v;
    __syncthreads();
  }
  int base = (t > 0) ? part[t - 1] : 0;
#pragma unroll
  for (int j = 0; j < 16; ++j) {
    int rs = base + loc[j];
    rowstart[t * 16 + j] = rs;
    cursor[t * 16 + j] = rs;
  }
  if (t == 255) rowstart[4096] = part[255];
}

__global__ __launch_bounds__(256) void csr_fill_k(const int* __restrict__ ei,
                                                  const float* __restrict__ dinv,
                                                  int* __restrict__ cursor,
                                                  int* __restrict__ ecol,
                                                  float* __restrict__ ewt) {
  int e = blockIdx.x * 256 + threadIdx.x;
  int s = ei[e], d = ei[EE + e];
  int pos = atomicAdd(&cursor[d], 1);
  ecol[pos] = s;
  ewt[pos] = dinv[s] * dinv[d];
}

// ---------------------------------------------------------------- converts
__global__ __launch_bounds__(256) void cvt_k(const float* __restrict__ s,
                                             unsigned short* __restrict__ d, int n4) {
  int i = blockIdx.x * 256 + threadIdx.x;
  if (i < n4) {
    f32x4 v = *(const f32x4*)&s[i * 4];
    u16x4 o;
#pragma unroll
    for (int j = 0; j < 4; ++j) o[j] = f2bf(v[j]);
    *(u16x4*)&d[i * 4] = o;
  }
}

struct P8 { const float* p[8]; };
// 8 weight matrices [512x512] f32 -> bf16, one kernel (blockIdx.y selects)
__global__ __launch_bounds__(256) void cvt8_k(P8 s, unsigned short* __restrict__ d) {
  const int which = blockIdx.y;
  const float* src = s.p[which];
  unsigned short* dst = d + (size_t)which * 262144;
  int i = blockIdx.x * 256 + threadIdx.x;
  f32x4 v = *(const f32x4*)&src[i * 4];
  u16x4 o;
#pragma unroll
  for (int j = 0; j < 4; ++j) o[j] = f2bf(v[j]);
  *(u16x4*)&dst[i * 4] = o;
}

// Wg[z] [512 k][512 j] f32 -> WgT [512 j][512 k] bf16 (both layers in one grid)
__global__ __launch_bounds__(256) void wtr2_k(const float* __restrict__ in,
                                              unsigned short* __restrict__ out) {
  __shared__ unsigned short sm[64][72];
  const int z = blockIdx.z;
  const float* inz = in + (size_t)z * DD * DD;
  unsigned short* outz = out + (size_t)z * 262144;
  const int k0 = blockIdx.y * 64, j0 = blockIdx.x * 64;
  const int t = threadIdx.x;
  const int r = t >> 2, q = (t & 3) * 16;
  const float* src = inz + (size_t)(k0 + r) * 512 + j0 + q;
#pragma unroll
  for (int jj = 0; jj < 16; ++jj) sm[r][q + jj] = f2bf(src[jj]);
  __syncthreads();
  short8 s0, s1;
#pragma unroll
  for (int j = 0; j < 8; ++j) {
    s0[j] = (short)sm[q + j][r];
    s1[j] = (short)sm[q + 8 + j][r];
  }
  *(short8*)&outz[(size_t)(j0 + r) * 512 + k0 + q] = s0;
  *(short8*)&outz[(size_t)(j0 + r) * 512 + k0 + q + 8] = s1;
}

// ---------------------------------------------------------------- GCN aggregation (bf16 in, f32 out)
// Also zeroes colsum/sumsq for the following colstat (block 0).
__global__ __launch_bounds__(256) void gather_k(const unsigned short* __restrict__ hb,
                                                const int* __restrict__ rowstart,
                                                const int* __restrict__ ecol,
                                                const float* __restrict__ ewt,
                                                float* __restrict__ h1,
                                                float* __restrict__ colsum) {
  __shared__ int s_col[256];
  __shared__ float s_w[256];
  const int node = blockIdx.x, t = threadIdx.x;
  if (node == 0) {  // zero colsum[512] + sumsq (adjacent); done before this kernel ends
    colsum[t] = 0.f;
    colsum[t + 256] = 0.f;
    if (t == 0) colsum[512] = 0.f;
  }
  const int beg = rowstart[node], end = rowstart[node + 1];
  float a0 = 0.f, a1 = 0.f, b0 = 0.f, b1 = 0.f;
  for (int base = beg; base < end; base += 256) {
    int n = min(256, end - base);
    __syncthreads();
    if (t < n) {
      s_col[t] = ecol[base + t];
      s_w[t] = ewt[base + t];
    }
    __syncthreads();
    int j = 0;
    for (; j + 3 < n; j += 4) {
      int c0 = s_col[j], c1 = s_col[j + 1], c2 = s_col[j + 2], c3 = s_col[j + 3];
      float e0 = s_w[j], e1 = s_w[j + 1], e2 = s_w[j + 2], e3 = s_w[j + 3];
      unsigned v0 = *(const unsigned*)&hb[(size_t)c0 * DD + 2 * t];
      unsigned v1 = *(const unsigned*)&hb[(size_t)c1 * DD + 2 * t];
      unsigned v2 = *(const unsigned*)&hb[(size_t)c2 * DD + 2 * t];
      unsigned v3 = *(const unsigned*)&hb[(size_t)c3 * DD + 2 * t];
      a0 += e0 * __uint_as_float(v0 << 16);
      a1 += e0 * __uint_as_float(v0 & 0xFFFF0000u);
      b0 += e1 * __uint_as_float(v1 << 16);
      b1 += e1 * __uint_as_float(v1 & 0xFFFF0000u);
      a0 += e2 * __uint_as_float(v2 << 16);
      a1 += e2 * __uint_as_float(v2 & 0xFFFF0000u);
      b0 += e3 * __uint_as_float(v3 << 16);
      b1 += e3 * __uint_as_float(v3 & 0xFFFF0000u);
    }
    for (; j < n; ++j) {
      int c = s_col[j];
      float en = s_w[j];
      unsigned v = *(const unsigned*)&hb[(size_t)c * DD + 2 * t];
      a0 += en * __uint_as_float(v << 16);
      a1 += en * __uint_as_float(v & 0xFFFF0000u);
    }
  }
  f32x2 acc = {a0 + b0, a1 + b1};
  *(f32x2*)&h1[(size_t)node * DD + 2 * t] = acc;
}

// ---------------------------------------------------------------- bf16 GEMM (m97-style)
// C[M,Nc] = A[M,K] @ B[Nc,K]^T (both bf16), epilogue (acc+bias)*scale.
template <bool HAS_BIAS, bool OUT_BF16>
__global__ __launch_bounds__(256) void gemm_bt_k(const unsigned short* __restrict__ A,
                                                 const unsigned short* __restrict__ B,
                                                 const float* __restrict__ bias, float scale,
                                                 void* __restrict__ Cv, int M, int Nc, int K) {
  __shared__ __align__(16) unsigned short a_sm[2][64][64];
  __shared__ __align__(16) unsigned short b_sm[2][64][64];
  const int tid = threadIdx.x, w = tid >> 6, lane = tid & 63;
  const int g = lane >> 4, c16 = lane & 15;
  const int n0 = blockIdx.x * 64, m0 = blockIdx.y * 64;
  const int wm = (w >> 1) * 32, wn = (w & 1) * 32;
  const int srow = lane >> 3, cg = lane & 7;
  const int swz = ((cg * 16) ^ (srow << 4)) >> 1;
  const unsigned short* ag = A + (size_t)(m0 + w * 8 + srow) * K + swz;
  const unsigned short* bg = B + (size_t)(n0 + w * 8 + srow) * K + swz;
  f32x4 acc[2][2] = {};

  gload16(ag, &a_sm[0][w * 8][0]);
  gload16(ag + (size_t)32 * K, &a_sm[0][w * 8 + 32][0]);
  gload16(bg, &b_sm[0][w * 8][0]);
  gload16(bg + (size_t)32 * K, &b_sm[0][w * 8 + 32][0]);
  __syncthreads();

  const int rx = (c16 & 7) << 4;
  const int NK = K >> 6;
  for (int ks = 0; ks < NK; ++ks) {
    const int cb = ks & 1;
    if (ks < NK - 1) {
      const size_t ko = (size_t)(ks + 1) * 64;
      gload16(ag + ko, &a_sm[cb ^ 1][w * 8][0]);
      gload16(ag + ko + (size_t)32 * K, &a_sm[cb ^ 1][w * 8 + 32][0]);
      gload16(bg + ko, &b_sm[cb ^ 1][w * 8][0]);
      gload16(bg + ko + (size_t)32 * K, &b_sm[cb ^ 1][w * 8 + 32][0]);
    }
#pragma unroll
    for (int kc = 0; kc < 2; ++kc) {
      const int co = (kc * 64 + g * 16) ^ rx;
      short8 af0 = *(const short8*)((const char*)&a_sm[cb][wm + c16][0] + co);
      short8 af1 = *(const short8*)((const char*)&a_sm[cb][wm + 16 + c16][0] + co);
      short8 bf0 = *(const short8*)((const char*)&b_sm[cb][wn + c16][0] + co);
      short8 bf1 = *(const short8*)((const char*)&b_sm[cb][wn + 16 + c16][0] + co);
      acc[0][0] = mfma16(af0, bf0, acc[0][0]);
      acc[0][1] = mfma16(af0, bf1, acc[0][1]);
      acc[1][0] = mfma16(af1, bf0, acc[1][0]);
      acc[1][1] = mfma16(af1, bf1, acc[1][1]);
    }
    __syncthreads();
  }
#pragma unroll
  for (int fm = 0; fm < 2; ++fm)
#pragma unroll
    for (int fn = 0; fn < 2; ++fn)
#pragma unroll
      for (int r = 0; r < 4; ++r) {
        int row = m0 + wm + fm * 16 + g * 4 + r;
        int col = n0 + wn + fn * 16 + c16;
        float v = acc[fm][fn][r];
        if (HAS_BIAS) v += bias[col];
        v *= scale;
        if (OUT_BF16)
          ((unsigned short*)Cv)[(size_t)row * Nc + col] = f2bf(v);
        else
          ((float*)Cv)[(size_t)row * Nc + col] = v;
      }
}

// ---------------------------------------------------------------- fused QKV GEMM
// Nc_total = 1536; col block selects {Q,K,V} weight, bias, scale, target.
// Q scale carries log2(e) for log2-domain softmax.
__global__ __launch_bounds__(256) void gemm_qkv_k(const unsigned short* __restrict__ A,
                                                  const unsigned short* __restrict__ wbase,
                                                  const float* __restrict__ bq,
                                                  const float* __restrict__ bk,
                                                  const float* __restrict__ bv,
                                                  unsigned short* __restrict__ Qo,
                                                  unsigned short* __restrict__ Ko,
                                                  unsigned short* __restrict__ Vo,
                                                  int layer) {
  __shared__ __align__(16) unsigned short a_sm[2][64][64];
  __shared__ __align__(16) unsigned short b_sm[2][64][64];
  const int tid = threadIdx.x, w = tid >> 6, lane = tid & 63;
  const int g = lane >> 4, c16 = lane & 15;
  const int n0g = blockIdx.x * 64, m0 = blockIdx.y * 64;
  const int which = n0g >> 9;           // 0=Q 1=K 2=V
  const int n0 = n0g & 511;             // local col base
  const unsigned short* B = wbase + (size_t)(which * 2 + layer) * 262144;
  const float* bias = which == 0 ? bq : (which == 1 ? bk : bv);
  const float scale = which == 0 ? SCALE_Q : (which == 1 ? SCALE_K : 1.f);
  unsigned short* dst = which == 0 ? Qo : (which == 1 ? Ko : Vo);
  const int K = DD;
  const int wm = (w >> 1) * 32, wn = (w & 1) * 32;
  const int srow = lane >> 3, cg = lane & 7;
  const int swz = ((cg * 16) ^ (srow << 4)) >> 1;
  const unsigned short* ag = A + (size_t)(m0 + w * 8 + srow) * K + swz;
  const unsigned short* bg = B + (size_t)(n0 + w * 8 + srow) * K + swz;
  f32x4 acc[2][2] = {};

  gload16(ag, &a_sm[0][w * 8][0]);
  gload16(ag + (size_t)32 * K, &a_sm[0][w * 8 + 32][0]);
  gload16(bg, &b_sm[0][w * 8][0]);
  gload16(bg + (size_t)32 * K, &b_sm[0][w * 8 + 32][0]);
  __syncthreads();

  const int rx = (c16 & 7) << 4;
  const int NK = K >> 6;
  for (int ks = 0; ks < NK; ++ks) {
    const int cb = ks & 1;
    if (ks < NK - 1) {
      const size_t ko = (size_t)(ks + 1) * 64;
      gload16(ag + ko, &a_sm[cb ^ 1][w * 8][0]);
      gload16(ag + ko + (size_t)32 * K, &a_sm[cb ^ 1][w * 8 + 32][0]);
      gload16(bg + ko, &b_sm[cb ^ 1][w * 8][0]);
      gload16(bg + ko + (size_t)32 * K, &b_sm[cb ^ 1][w * 8 + 32][0]);
    }
#pragma unroll
    for (int kc = 0; kc < 2; ++kc) {
      const int co = (kc * 64 + g * 16) ^ rx;
      short8 af0 = *(const short8*)((const char*)&a_sm[cb][wm + c16][0] + co);
      short8 af1 = *(const short8*)((const char*)&a_sm[cb][wm + 16 + c16][0] + co);
      short8 bf0 = *(const short8*)((const char*)&b_sm[cb][wn + c16][0] + co);
      short8 bf1 = *(const short8*)((const char*)&b_sm[cb][wn + 16 + c16][0] + co);
      acc[0][0] = mfma16(af0, bf0, acc[0][0]);
      acc[0][1] = mfma16(af0, bf1, acc[0][1]);
      acc[1][0] = mfma16(af1, bf0, acc[1][0]);
      acc[1][1] = mfma16(af1, bf1, acc[1][1]);
    }
    __syncthreads();
  }
#pragma unroll
  for (int fm = 0; fm < 2; ++fm)
#pragma unroll
    for (int fn = 0; fn < 2; ++fn)
#pragma unroll
      for (int r = 0; r < 4; ++r) {
        int row = m0 + wm + fm * 16 + g * 4 + r;
        int col = n0 + wn + fn * 16 + c16;
        float v = (acc[fm][fn][r] + bias[col]) * scale;
        dst[(size_t)row * DD + col] = f2bf(v);
      }
}

// ---------------------------------------------------------------- PairNorm stats
__global__ __launch_bounds__(256) void colstat_k(const float* __restrict__ hin,
                                                 float* __restrict__ colsum,
                                                 float* __restrict__ sumsq) {
  const int t = threadIdx.x;
  const int r0 = blockIdx.x * 32;
  float a0 = 0.f, a1 = 0.f, sq = 0.f;
  for (int r = 0; r < 32; ++r) {
    float v0 = hin[(size_t)(r0 + r) * DD + t];
    float v1 = hin[(size_t)(r0 + r) * DD + 256 + t];
    a0 += v0; a1 += v1;
    sq += v0 * v0 + v1 * v1;
  }
  atomicAdd(&colsum[t], a0);
  atomicAdd(&colsum[t + 256], a1);
#pragma unroll
  for (int m = 1; m <= 32; m <<= 1) sq += __shfl_xor(sq, m);
  __shared__ float rr[4];
  int w = t >> 6, lane = t & 63;
  if (lane == 0) rr[w] = sq;
  __syncthreads();
  if (t == 0) atomicAdd(sumsq, rr[0] + rr[1] + rr[2] + rr[3]);
}

__global__ __launch_bounds__(256) void finalize_pn_k(const float* __restrict__ colsum,
                                                     const float* __restrict__ sumsq,
                                                     float* __restrict__ mu,
                                                     float* __restrict__ rnp) {
  const int t = threadIdx.x;
  float m0 = colsum[t] * (1.f / (float)NN);
  float m1 = colsum[t + 256] * (1.f / (float)NN);
  mu[t] = m0;
  mu[t + 256] = m1;
  float sq = m0 * m0 + m1 * m1;
#pragma unroll
  for (int m = 1; m <= 32; m <<= 1) sq += __shfl_xor(sq, m);
  __shared__ float rr[4];
  int w = t >> 6, lane = t & 63;
  if (lane == 0) rr[w] = sq;
  __syncthreads();
  if (t == 0) {
    float musq = rr[0] + rr[1] + rr[2] + rr[3];
    *rnp = rsqrtf(1e-5f + (*sumsq) * (1.f / (float)NN) - musq);
  }
}

// ---------------------------------------------------------------- fused row ops
template <bool PN, bool WF32>
__global__ __launch_bounds__(256) void rowfuse_k(const float* __restrict__ hin,
                                                 const float* __restrict__ mu,
                                                 const float* __restrict__ rnp,
                                                 const float* __restrict__ gg,
                                                 const float* __restrict__ bb,
                                                 float* __restrict__ outf,
                                                 unsigned short* __restrict__ outb) {
  const int row = blockIdx.x, t = threadIdx.x;
  const size_t base = (size_t)row * DD;
  f32x2 vv = *(const f32x2*)&hin[base + 2 * t];
  float v0 = vv[0], v1 = vv[1];
  if (PN) {
    float rn = *rnp;
    v0 = (v0 - mu[2 * t]) * rn;
    v1 = (v1 - mu[2 * t + 1]) * rn;
    v0 = fmaxf(v0, 0.f) + v0;
    v1 = fmaxf(v1, 0.f) + v1;
  }
  float s1 = v0 + v1, s2 = v0 * v0 + v1 * v1;
#pragma unroll
  for (int m = 1; m <= 32; m <<= 1) {
    s1 += __shfl_xor(s1, m);
    s2 += __shfl_xor(s2, m);
  }
  __shared__ float r1[4], r2[4];
  int w = t >> 6, lane = t & 63;
  if (lane == 0) { r1[w] = s1; r2[w] = s2; }
  __syncthreads();
  s1 = r1[0] + r1[1] + r1[2] + r1[3];
  s2 = r2[0] + r2[1] + r2[2] + r2[3];
  float mean = s1 * (1.f / (float)DD);
  float var = s2 * (1.f / (float)DD) - mean * mean;
  float inv = rsqrtf(var + 1e-5f);
  float y0 = (v0 - mean) * inv * gg[2 * t] + bb[2 * t];
  float y1 = (v1 - mean) * inv * gg[2 * t + 1] + bb[2 * t + 1];
  if (WF32) {
    f32x2 yo = {y0, y1};
    *(f32x2*)&outf[base + 2 * t] = yo;
  }
  *(unsigned*)&outb[base + 2 * t] = (unsigned)f2bf(y0) | ((unsigned)f2bf(y1) << 16);
}

// ---------------------------------------------------------------- dual [512][4096] -> [4096][512] bf16 transpose
__global__ __launch_bounds__(256) void transpose2_pk(const unsigned short* __restrict__ in0,
                                                     const unsigned short* __restrict__ in1,
                                                     unsigned short* __restrict__ out0,
                                                     unsigned short* __restrict__ out1) {
  __shared__ __align__(16) unsigned short sm[64][72];
  const unsigned short* in = blockIdx.z ? in1 : in0;
  unsigned short* out = blockIdx.z ? out1 : out0;
  const int m0 = blockIdx.x * 64, p0 = blockIdx.y * 64;
  const int t = threadIdx.x;
  const int r = t >> 2, q = (t & 3) * 16;
  *(short8*)&sm[r][q] = *(const short8*)&in[(size_t)(p0 + r) * NN + m0 + q];
  *(short8*)&sm[r][q + 8] = *(const short8*)&in[(size_t)(p0 + r) * NN + m0 + q + 8];
  __syncthreads();
  short8 s0, s1;
#pragma unroll
  for (int j = 0; j < 8; ++j) {
    s0[j] = (short)sm[q + j][r];
    s1[j] = (short)sm[q + 8 + j][r];
  }
  *(short8*)&out[(size_t)(m0 + r) * DD + p0 + q] = s0;
  *(short8*)&out[(size_t)(m0 + r) * DD + p0 + q + 8] = s1;
}

// ---------------------------------------------------------------- flash attention, split-K
// log2-domain softmax (S already scaled by log2e via Q scale); XCD-swizzled
// 1D grid: each XCD owns 2 (h,z) combos -> 1MB L2 working set.
__global__ __launch_bounds__(256, 4) void attn_k(const unsigned short* __restrict__ Qt,
                                                 const unsigned short* __restrict__ Kt,
                                                 const unsigned short* __restrict__ Vb,
                                                 unsigned short* __restrict__ Op0,
                                                 unsigned short* __restrict__ Op1,
                                                 float* __restrict__ ms) {
  __shared__ __align__(16) unsigned short k_sm[2][64][64];
  __shared__ __align__(16) unsigned short v_sm[2][64][64];
  __shared__ __align__(16) unsigned short p_sm[4][16][64];
  const int tid = threadIdx.x, w = tid >> 6, lane = tid & 63;
  const int g = lane >> 4, c16 = lane & 15;
  // XCD-aware decode: L%8 = XCD; combo c = xcd + 8*(slot>>6); xblk = slot&63
  const int L = blockIdx.x;
  const int xcd = L & 7, slot = L >> 3;
  const int c = xcd + 8 * (slot >> 6);
  const int h = c >> 1, z = c & 1;
  const int zbase = z * (NN / 2);
  const int l0 = (slot & 63) * 64 + w * 16;
  unsigned short* __restrict__ Op = z ? Op1 : Op0;

  short8 qf0 = *(const short8*)&Qt[(size_t)(l0 + c16) * DD + h * 64 + g * 8];
  short8 qf1 = *(const short8*)&Qt[(size_t)(l0 + c16) * DD + h * 64 + 32 + g * 8];

  const int srow = lane >> 3, cg = lane & 7;
  const int swz = ((cg * 16) ^ (srow << 4)) >> 1;
  const unsigned short* kgbase = Kt + (size_t)(zbase + w * 16 + srow) * DD + h * 64 + swz;
  const unsigned short* vgbase = Vb + (size_t)(h * 64 + w * 16 + srow) * NN + zbase + swz;

  gload16(kgbase, &k_sm[0][w * 16][0]);
  gload16(kgbase + (size_t)8 * DD, &k_sm[0][w * 16 + 8][0]);
  gload16(vgbase, &v_sm[0][w * 16][0]);
  gload16(vgbase + (size_t)8 * NN, &v_sm[0][w * 16 + 8][0]);
  __syncthreads();

  float M = 0.f;          // log2-domain running max ref
  f32x4 sacc = {};        // row sums via ones-column MFMA
  f32x4 oacc[4] = {};
  const int sx = (c16 & 7) << 4;
  short8 ones8;
#pragma unroll
  for (int j = 0; j < 8; ++j) ones8[j] = (short)0x3F80;  // bf16 1.0

  for (int t = 0; t < 32; ++t) {
    const int cb = t & 1;
    if (t < 31) {
      const size_t ko = (size_t)(t + 1) * 64 * DD;
      gload16(kgbase + ko, &k_sm[cb ^ 1][w * 16][0]);
      gload16(kgbase + ko + (size_t)8 * DD, &k_sm[cb ^ 1][w * 16 + 8][0]);
      gload16(vgbase + (t + 1) * 64, &v_sm[cb ^ 1][w * 16][0]);
      gload16(vgbase + (t + 1) * 64 + (size_t)8 * NN, &v_sm[cb ^ 1][w * 16 + 8][0]);
    }
    // QK^T (S in log2 domain)
    f32x4 sf[4] = {};
#pragma unroll
    for (int fn = 0; fn < 4; ++fn) {
      const char* kr = (const char*)&k_sm[cb][fn * 16 + c16][0];
      short8 b0 = *(const short8*)(kr + ((g * 16) ^ sx));
      short8 b1 = *(const short8*)(kr + ((64 + g * 16) ^ sx));
      sf[fn] = mfma16(qf0, b0, sf[fn]);
      sf[fn] = mfma16(qf1, b1, sf[fn]);
    }
    // overflow guard (cold); 36.1 = 25 * log2(e)
    float a0 = fmaxf(fmaxf(sf[0][0], sf[0][1]), fmaxf(sf[0][2], sf[0][3]));
    float a1 = fmaxf(fmaxf(sf[1][0], sf[1][1]), fmaxf(sf[1][2], sf[1][3]));
    float a2 = fmaxf(fmaxf(sf[2][0], sf[2][1]), fmaxf(sf[2][2], sf[2][3]));
    float a3 = fmaxf(fmaxf(sf[3][0], sf[3][1]), fmaxf(sf[3][2], sf[3][3]));
    float amax = fmaxf(fmaxf(a0, a1), fmaxf(a2, a3));
    if (__any(amax > M + 36.1f)) {
      float wmax = amax;
#pragma unroll
      for (int m = 1; m <= 32; m <<= 1) wmax = fmaxf(wmax, __shfl_xor(wmax, m));
      float alpha = exp2f(M - wmax);
#pragma unroll
      for (int r = 0; r < 4; ++r) sacc[r] *= alpha;
#pragma unroll
      for (int fd = 0; fd < 4; ++fd)
#pragma unroll
        for (int r = 0; r < 4; ++r) oacc[fd][r] *= alpha;
      M = wmax;
    }
#pragma unroll
    for (int fn = 0; fn < 4; ++fn)
#pragma unroll
      for (int r = 0; r < 4; ++r) sf[fn][r] = exp2f(sf[fn][r] - M);  // native v_exp
    // P -> per-wave LDS strip (A-operand layout), XOR-swizzled by row
#pragma unroll
    for (int fn = 0; fn < 4; ++fn)
#pragma unroll
      for (int r = 0; r < 4; ++r) {
        const int prow = g * 4 + r;
        const int pb = ((fn * 16 + c16) * 2) ^ ((prow & 7) << 4);
        *(unsigned short*)((char*)&p_sm[w][prow][0] + pb) = f2bf(sf[fn][r]);
      }
    // PV + ones-column row-sum (both on MFMA pipe); read applies same XOR
#pragma unroll
    for (int kk = 0; kk < 2; ++kk) {
      const int rb = (kk * 64 + g * 16) ^ ((c16 & 7) << 4);
      short8 pa = *(const short8*)((const char*)&p_sm[w][c16][0] + rb);
      sacc = mfma16(pa, ones8, sacc);
#pragma unroll
      for (int fd = 0; fd < 4; ++fd) {
        const char* vr = (const char*)&v_sm[cb][fd * 16 + c16][0];
        short8 vbf = *(const short8*)(vr + ((kk * 64 + g * 16) ^ sx));
        oacc[fd] = mfma16(pa, vbf, oacc[fd]);
      }
    }
    __syncthreads();
  }
#pragma unroll
  for (int fd = 0; fd < 4; ++fd)
#pragma unroll
    for (int r = 0; r < 4; ++r) {
      int l = l0 + g * 4 + r;
      Op[((size_t)h * NN + l) * DH + fd * 16 + c16] = f2bf(oacc[fd][r]);
    }
  if (c16 == 0) {
#pragma unroll
    for (int r = 0; r < 4; ++r) {
      int hl = h * NN + l0 + g * 4 + r;
      f32x2 pr = {M, sacc[r]};
      *(f32x2*)&ms[((size_t)z * (HH * NN) + hl) * 2] = pr;
    }
  }
}

// merge halves (M in log2 domain): out = (w0*O0 + w1*O1)/(w0*s0 + w1*s1)
__global__ __launch_bounds__(256) void attn_merge_k(const unsigned short* __restrict__ Op0,
                                                    const unsigned short* __restrict__ Op1,
                                                    const float* __restrict__ ms,
                                                    unsigned short* __restrict__ Out) {
  const int t = threadIdx.x;
  const int hl = blockIdx.x * 4 + (t >> 6);
  const int d = t & 63;
  float M0 = ms[(size_t)hl * 2], s0 = ms[(size_t)hl * 2 + 1];
  float M1 = ms[((size_t)(HH * NN) + hl) * 2], s1 = ms[((size_t)(HH * NN) + hl) * 2 + 1];
  float M = fmaxf(M0, M1);
  float w0 = exp2f(M0 - M), w1 = exp2f(M1 - M);
  float inv = 1.f / (w0 * s0 + w1 * s1);
  size_t idx = (size_t)hl * DH + d;
  Out[idx] = f2bf((w0 * bf2f(Op0[idx]) + w1 * bf2f(Op1[idx])) * inv);
}

// ---------------------------------------------------------------- launch
extern "C" void kernel_launch(void* const* d_in, const int* in_sizes, int n_in,
                              void* d_out, int out_size, void* d_ws, size_t ws_size,
                              hipStream_t stream) {
  const float* x = (const float*)d_in[0];
  const int* ei = (const int*)d_in[1];
  const float* Wg = (const float*)d_in[3];
  const float* ln1g = (const float*)d_in[4];
  const float* ln1b = (const float*)d_in[5];
  const float* Wq = (const float*)d_in[6];
  const float* bq = (const float*)d_in[7];
  const float* Wk = (const float*)d_in[8];
  const float* bk = (const float*)d_in[9];
  const float* Wv = (const float*)d_in[10];
  const float* bv = (const float*)d_in[11];
  const float* Wo = (const float*)d_in[12];
  const float* bo = (const float*)d_in[13];
  const float* ln2g = (const float*)d_in[14];
  const float* ln2b = (const float*)d_in[15];
  float* out = (float*)d_out;

  // ---- workspace layout
  char* p = (char*)d_ws;
  float* deg = (float*)p;            // 4096
  float* dinv = deg + 4096;          // 4096
  float* colsum = deg + 8192;        // 512 (+sumsq adjacent)
  float* sumsq = deg + 8704;         // 1
  float* mu = deg + 8768;            // 512
  float* rnp = deg + 9280;           // 1
  float* h1 = deg + 16384;           // [4096][512] f32 (gather out / Wo out)
  unsigned short* xb = (unsigned short*)(h1 + (1u << 21));  // 7 bf16 act buffers, 2M shorts each
  unsigned short* actb = xb + (1u << 21);
  unsigned short* h4b = actb + (1u << 21);
  unsigned short* proj = h4b + (1u << 21);
  unsigned short* Vb = proj + (1u << 21);
  unsigned short* Qt = Vb + (1u << 21);
  unsigned short* Kt = Qt + (1u << 21);
  unsigned short* wb = Kt + (1u << 21);  // 10 x 262144 shorts
  float* msbuf = (float*)(wb + 10u * 262144);  // 131072 f32
  int* rowstart = (int*)(msbuf + 131072);      // 4104
  int* cursor = rowstart + 4104;               // 4096
  int* ecol = cursor + 4096;                   // E
  float* ewt = (float*)(ecol + EE);            // E
  const size_t needed = (size_t)((char*)(ewt + EE) - (char*)d_ws);
  if (ws_size < needed) return;

  unsigned short* Op0b = (unsigned short*)h1;  // dead f32 region during attn
  unsigned short* Op1b = h4b;                  // dead after QKV gemm

  const size_t WS = (size_t)DD * DD;

  hipMemsetAsync(deg, 0, 4096 * sizeof(float), stream);
  deg_k<<<EE / 256, 256, 0, stream>>>(ei, deg);
  dinv_k<<<NN / 256, 256, 0, stream>>>(deg, dinv);
  scan_k<<<1, 256, 0, stream>>>(deg, rowstart, cursor);
  csr_fill_k<<<EE / 256, 256, 0, stream>>>(ei, dinv, cursor, ecol, ewt);

  // one-time converts: x, Wg (transposed, both layers), 8 projection weights
  cvt_k<<<2048, 256, 0, stream>>>(x, xb, 524288);
  wtr2_k<<<dim3(8, 8, 2), 256, 0, stream>>>(Wg, wb);
  P8 s8;
  s8.p[0] = Wq; s8.p[1] = Wq + WS;
  s8.p[2] = Wk; s8.p[3] = Wk + WS;
  s8.p[4] = Wv; s8.p[5] = Wv + WS;
  s8.p[6] = Wo; s8.p[7] = Wo + WS;
  cvt8_k<<<dim3(256, 8), 256, 0, stream>>>(s8, wb + 2u * 262144);

  const dim3 gg(8, 64);
  for (int i = 0; i < 2; ++i) {
    // GCN: actb = xb @ WgT^T (bf16)
    gemm_bt_k<false, true><<<gg, 256, 0, stream>>>(
        xb, wb + (0 + i) * 262144, nullptr, 1.f, actb, NN, DD, DD);
    gather_k<<<NN, 256, 0, stream>>>(actb, rowstart, ecol, ewt, h1, colsum);
    colstat_k<<<128, 256, 0, stream>>>(h1, colsum, sumsq);
    finalize_pn_k<<<1, 256, 0, stream>>>(colsum, sumsq, mu, rnp);
    rowfuse_k<true, false><<<NN, 256, 0, stream>>>(h1, mu, rnp, ln1g + i * DD, ln1b + i * DD,
                                                   nullptr, h4b);
    // fused QKV projection: Q -> proj, K -> actb, V -> Vb
    gemm_qkv_k<<<dim3(24, 64), 256, 0, stream>>>(
        h4b, wb + 2u * 262144, bq + i * DD, bk + i * DD, bv + i * DD, proj, actb, Vb, i);
    transpose2_pk<<<dim3(64, 8, 2), 256, 0, stream>>>(proj, actb, Qt, Kt);
    // attention (split-K=2, XCD-swizzled 1D grid)
    attn_k<<<1024, 256, 0, stream>>>(Qt, Kt, Vb, Op0b, Op1b, msbuf);
    attn_merge_k<<<HH * NN / 4, 256, 0, stream>>>(Op0b, Op1b, msbuf, actb);
    // output projection + LN2
    gemm_bt_k<true, false><<<gg, 256, 0, stream>>>(
        actb, wb + (8 + i) * 262144, bo + i * DD, 1.f, h1, NN, DD, DD);
    rowfuse_k<false, true><<<NN, 256, 0, stream>>>(h1, nullptr, nullptr, ln2g + i * DD,
                                                   ln2b + i * DD, out, xb);
  }
}